// Round 1
// baseline (1004.704 us; speedup 1.0000x reference)
//
#include <hip/hip_runtime.h>
#include <math.h>

namespace {

constexpr int BB   = 2;
constexpr int CC   = 48;
constexpr int NHEAD= 8;
constexpr int CPH  = 6;     // channels per head
constexpr int HID  = 127;   // int(48*2.66)
constexpr int QKVC = 144;
constexpr int PINC = 254;
constexpr int N1   = 256*256;
constexpr int N2   = 128*128;
constexpr size_t PS2 = (size_t)BB*CC*N2;   // one nlwt plane
constexpr size_t NB1 = (size_t)BB*CC*N1;

// stats layout (floats, relative to stats base):
// [0,96)    q sum-sq      (b*48 + ch)
// [96,192)  k sum-sq
// [192,768) gram          ((b*8+h)*36 + c*6+d)
// [768,1344) attn weights ((b*8+h)*36 + c*6+d)
// [1344,1536) gfm channel avg (b*96+ch)
// [1536,1728) gfm channel max
// [1728,1920) gfm cw

__device__ __forceinline__ float geluf(float x) {
    return 0.5f * x * (1.0f + erff(x * 0.70710678118654752440f));
}

__global__ void k_zero(float* __restrict__ p, int n)
{
    int i = blockIdx.x*256 + threadIdx.x;
    if (i < n) p[i] = 0.f;
}

// ---------------- LN (channel) + 1x1 conv ----------------
template<int CHUNK>
__device__ __forceinline__ void conv_chunk(const float* __restrict__ Wt, int ocb,
                                           const float (&xv)[CC], float* __restrict__ ob,
                                           int Ns)
{
    float acc[CHUNK];
#pragma unroll
    for (int i = 0; i < CHUNK; ++i) acc[i] = 0.f;
#pragma unroll
    for (int c = 0; c < CC; ++c) {
        float xc = xv[c];
#pragma unroll
        for (int i = 0; i < CHUNK; ++i)
            acc[i] = fmaf(xc, Wt[(ocb + i) * CC + c], acc[i]);
    }
#pragma unroll
    for (int i = 0; i < CHUNK; ++i) ob[(size_t)(ocb + i) * Ns] = acc[i];
}

template<int OC>
__global__ __launch_bounds__(256) void k_ln_conv(const float* __restrict__ X,
                       const float* __restrict__ lw, const float* __restrict__ lb,
                       const float* __restrict__ Wt, float* __restrict__ out, int Ns)
{
    int g = blockIdx.x * 256 + threadIdx.x;
    int b = g / Ns, p = g - b * Ns;
    int ocb = blockIdx.y * 16;
    const float* xb = X + (size_t)b * CC * Ns + p;
    float xv[CC];
    float s = 0.f, s2 = 0.f;
#pragma unroll
    for (int c = 0; c < CC; ++c) {
        float v = xb[(size_t)c * Ns];
        xv[c] = v; s += v; s2 += v * v;
    }
    float mu  = s * (1.0f / CC);
    float var = s2 * (1.0f / CC) - mu * mu;
    float inv = 1.0f / sqrtf(var + 1e-5f);
#pragma unroll
    for (int c = 0; c < CC; ++c)
        xv[c] = (xv[c] - mu) * inv * lw[c] + lb[c];
    float* ob = out + (size_t)b * OC * Ns + p;
    constexpr int R = (OC % 16 == 0) ? 16 : (OC % 16);
    if (ocb + 16 <= OC) conv_chunk<16>(Wt, ocb, xv, ob, Ns);
    else                conv_chunk<R>(Wt, ocb, xv, ob, Ns);
}

// ---------------- depthwise 3x3 (zero pad) ----------------
__global__ __launch_bounds__(256) void k_dw3(const float* __restrict__ in, const float* __restrict__ w,
                      float* __restrict__ out, int nch, int Hs, int Ws)
{
    int Ns = Hs * Ws;
    int g = blockIdx.x * 256 + threadIdx.x;
    int p = g % Ns, bc = g / Ns;
    int c = bc % nch;
    int y = p / Ws, x = p - y * Ws;
    const float* ip = in + (size_t)bc * Ns;
    const float* wc = w + c * 9;
    float s = 0.f;
#pragma unroll
    for (int ky = 0; ky < 3; ++ky) {
        int yy = y + ky - 1;
        bool yok = (yy >= 0) && (yy < Hs);
        int yc = yy < 0 ? 0 : (yy >= Hs ? Hs - 1 : yy);
#pragma unroll
        for (int kx = 0; kx < 3; ++kx) {
            int xx = x + kx - 1;
            bool ok = yok && (xx >= 0) && (xx < Ws);
            int xc = xx < 0 ? 0 : (xx >= Ws ? Ws - 1 : xx);
            float v = ip[(size_t)yc * Ws + xc];
            s = fmaf(ok ? v : 0.f, wc[ky * 3 + kx], s);
        }
    }
    out[(size_t)bc * Ns + p] = s;
}

// ---------------- q/k norms + gram reduction ----------------
__global__ __launch_bounds__(256) void k_qk_stats(const float* __restrict__ qkvd,
                                                  float* __restrict__ st, int Ns)
{
    const int NBLK = 32;
    int bh = blockIdx.x / NBLK, blk = blockIdx.x % NBLK;
    int b = bh / NHEAD, h = bh % NHEAD;
    const float* qb = qkvd + ((size_t)b*QKVC + h*CPH)*Ns;
    const float* kb = qkvd + ((size_t)b*QKVC + 48 + h*CPH)*Ns;
    float vals[48];
#pragma unroll
    for (int i = 0; i < 48; ++i) vals[i] = 0.f;
    for (int n = blk*256 + (int)threadIdx.x; n < Ns; n += NBLK*256) {
        float qv[CPH], kv[CPH];
#pragma unroll
        for (int i = 0; i < CPH; ++i) { qv[i] = qb[(size_t)i*Ns + n]; kv[i] = kb[(size_t)i*Ns + n]; }
#pragma unroll
        for (int i = 0; i < CPH; ++i) {
            vals[i]   = fmaf(qv[i], qv[i], vals[i]);
            vals[6+i] = fmaf(kv[i], kv[i], vals[6+i]);
        }
#pragma unroll
        for (int i = 0; i < CPH; ++i)
#pragma unroll
            for (int j = 0; j < CPH; ++j)
                vals[12 + i*6 + j] = fmaf(qv[i], kv[j], vals[12 + i*6 + j]);
    }
    __shared__ float red[4][48];
    int lane = threadIdx.x & 63, wave = threadIdx.x >> 6;
#pragma unroll
    for (int i = 0; i < 48; ++i) {
        float v = vals[i];
#pragma unroll
        for (int off = 32; off > 0; off >>= 1) v += __shfl_down(v, off);
        if (lane == 0) red[wave][i] = v;
    }
    __syncthreads();
    if ((int)threadIdx.x < 48) {
        int i = threadIdx.x;
        float v = red[0][i] + red[1][i] + red[2][i] + red[3][i];
        float* dst;
        if (i < 6)       dst = st + b*48 + h*CPH + i;
        else if (i < 12) dst = st + 96 + b*48 + h*CPH + (i-6);
        else             dst = st + 192 + (b*NHEAD+h)*36 + (i-12);
        atomicAdd(dst, v);
    }
}

// ---------------- tiny softmax over 6x6 per (b,h) ----------------
__global__ void k_attn(const float* __restrict__ st, const float* __restrict__ temp,
                       float* __restrict__ ao)
{
    int t = threadIdx.x;
    if (t >= BB*NHEAD) return;
    int b = t / NHEAD, h = t % NHEAD;
    const float* sqq = st + b*48 + h*CPH;
    const float* sqk = st + 96 + b*48 + h*CPH;
    const float* g   = st + 192 + (b*NHEAD+h)*36;
    float T = temp[h];
    float nq[CPH], nk[CPH];
#pragma unroll
    for (int i = 0; i < CPH; ++i) {
        nq[i] = fmaxf(sqrtf(sqq[i]), 1e-12f);
        nk[i] = fmaxf(sqrtf(sqk[i]), 1e-12f);
    }
    float* out = ao + (b*NHEAD+h)*36;
#pragma unroll
    for (int c = 0; c < CPH; ++c) {
        float l[CPH]; float m = -1e30f;
#pragma unroll
        for (int d = 0; d < CPH; ++d) {
            l[d] = g[c*6+d] / (nq[c]*nk[d]) * T;
            m = fmaxf(m, l[d]);
        }
        float ssum = 0.f;
#pragma unroll
        for (int d = 0; d < CPH; ++d) { l[d] = expf(l[d]-m); ssum += l[d]; }
        float r = 1.0f/ssum;
#pragma unroll
        for (int d = 0; d < CPH; ++d) out[c*6+d] = l[d]*r;
    }
}

// ---------------- attn @ v + proj 1x1 + residual ----------------
__global__ __launch_bounds__(256) void k_av_proj(const float* __restrict__ qkvd, const float* __restrict__ attn,
                          const float* __restrict__ projw, const float* __restrict__ X,
                          float* __restrict__ x1, int Ns)
{
    int g = blockIdx.x*256 + threadIdx.x;
    int b = g / Ns, p = g - b*Ns;
    const float* vb = qkvd + ((size_t)b*QKVC + 96)*Ns + p;
    float vv[CC];
#pragma unroll
    for (int c = 0; c < CC; ++c) vv[c] = vb[(size_t)c*Ns];
    const float* at = attn + b*288;
    float o[CC];
#pragma unroll
    for (int h = 0; h < NHEAD; ++h)
#pragma unroll
        for (int cc = 0; cc < CPH; ++cc) {
            float acc = 0.f;
#pragma unroll
            for (int d = 0; d < CPH; ++d)
                acc = fmaf(at[(h*CPH+cc)*CPH + d], vv[h*CPH + d], acc);
            o[h*CPH+cc] = acc;
        }
    const float* xb = X + (size_t)b*CC*Ns + p;
    float* ob = x1 + (size_t)b*CC*Ns + p;
    for (int ocb = 0; ocb < CC; ocb += 16) {
        float acc[16];
#pragma unroll
        for (int i = 0; i < 16; ++i) acc[i] = 0.f;
#pragma unroll
        for (int c = 0; c < CC; ++c) {
#pragma unroll
            for (int i = 0; i < 16; ++i)
                acc[i] = fmaf(o[c], projw[(ocb+i)*CC + c], acc[i]);
        }
#pragma unroll
        for (int i = 0; i < 16; ++i)
            ob[(size_t)(ocb+i)*Ns] = xb[(size_t)(ocb+i)*Ns] + acc[i];
    }
}

// ---------------- ffn: dw3x3 + gelu-gate + pout 1x1 + residual ----------------
__device__ __forceinline__ float dw9(const float* __restrict__ plane, const float* __restrict__ w9,
                                     int y, int x, int Hs, int Ws)
{
    float s = 0.f;
#pragma unroll
    for (int ky = 0; ky < 3; ++ky) {
        int yy = y + ky - 1;
        bool yok = (yy >= 0) && (yy < Hs);
        int yc = yy < 0 ? 0 : (yy >= Hs ? Hs-1 : yy);
#pragma unroll
        for (int kx = 0; kx < 3; ++kx) {
            int xx = x + kx - 1;
            bool ok = yok && (xx >= 0) && (xx < Ws);
            int xc = xx < 0 ? 0 : (xx >= Ws ? Ws-1 : xx);
            float v = plane[(size_t)yc*Ws + xc];
            s = fmaf(ok ? v : 0.f, w9[ky*3+kx], s);
        }
    }
    return s;
}

__global__ __launch_bounds__(256) void k_ffn(const float* __restrict__ pin, const float* __restrict__ dww,
                      const float* __restrict__ poutw, const float* __restrict__ x1,
                      float* __restrict__ out, int Hs, int Ws)
{
    int Ns = Hs*Ws;
    int g = blockIdx.x*256 + threadIdx.x;
    int b = g / Ns, p = g - b*Ns;
    int y = p / Ws, x = p - y*Ws;
    const float* pbase = pin + (size_t)b*PINC*Ns;
    float acc[CC];
#pragma unroll
    for (int i = 0; i < CC; ++i) acc[i] = 0.f;
    for (int c = 0; c < HID; ++c) {
        float d1 = dw9(pbase + (size_t)c*Ns,        dww + c*9,        y, x, Hs, Ws);
        float d2 = dw9(pbase + (size_t)(c+HID)*Ns,  dww + (c+HID)*9,  y, x, Hs, Ws);
        float tv = geluf(d1) * d2;
#pragma unroll
        for (int oc = 0; oc < CC; ++oc)
            acc[oc] = fmaf(tv, poutw[oc*HID + c], acc[oc]);
    }
    const float* xb = x1 + (size_t)b*CC*Ns + p;
    float* ob = out + (size_t)b*CC*Ns + p;
#pragma unroll
    for (int oc = 0; oc < CC; ++oc)
        ob[(size_t)oc*Ns] = xb[(size_t)oc*Ns] + acc[oc];
}

// ---------------- nlwt ----------------
__global__ __launch_bounds__(256) void k_nlwt(const float* __restrict__ X, float* __restrict__ A4)
{
    int g = blockIdx.x*256 + threadIdx.x;   // over BB*CC*N2
    int n = g & (N2-1); int bc = g >> 14;
    int h1 = n >> 7, w1 = n & 127;
    int hb = (h1+1)&127, wb = (w1+1)&127;
    const float* xp = X + (size_t)bc * N1;
    float t1, t2, t3, t4;
    {
        int y=h1, z=w1;
        float c0=xp[(2*y)*256+2*z], c1=xp[(2*y)*256+2*z+1], c2=xp[(2*y+1)*256+2*z], c3=xp[(2*y+1)*256+2*z+1];
        t1 = 0.5f*(-c0 - c1 - c2 + c3);
    }
    {
        int y=hb, z=w1;
        float c0=xp[(2*y)*256+2*z], c1=xp[(2*y)*256+2*z+1], c2=xp[(2*y+1)*256+2*z], c3=xp[(2*y+1)*256+2*z+1];
        t2 = 0.5f*( c0 - c1 + c2 + c3);
    }
    {
        int y=h1, z=wb;
        float c0=xp[(2*y)*256+2*z], c1=xp[(2*y)*256+2*z+1], c2=xp[(2*y+1)*256+2*z], c3=xp[(2*y+1)*256+2*z+1];
        t3 = 0.5f*( c0 + c1 - c2 + c3);
    }
    {
        int y=hb, z=wb;
        float c0=xp[(2*y)*256+2*z], c1=xp[(2*y)*256+2*z+1], c2=xp[(2*y+1)*256+2*z], c3=xp[(2*y+1)*256+2*z+1];
        t4 = 0.5f*( c0 - c1 - c2 - c3);
    }
    size_t o = (size_t)bc*N2 + n;
    A4[o]           = -t1 + t2 + t3 - t4;
    A4[PS2 + o]     = -t1 - t2 - t3 - t4;
    A4[2*PS2 + o]   = -t1 - t2 + t3 + t4;
    A4[3*PS2 + o]   =  t1 - t2 + t3 - t4;
}

// ---------------- inlwt ----------------
__global__ __launch_bounds__(256) void k_inlwt(const float* __restrict__ Ain, const float* __restrict__ A4,
                        float* __restrict__ out)
{
    int g = blockIdx.x*256 + threadIdx.x;   // over BB*CC*N2
    int n = g & (N2-1); int bc = g >> 14;
    int h1 = n >> 7, w1 = n & 127;
    int hm = (h1-1)&127, wm = (w1-1)&127;
    const float* I0 = Ain + (size_t)bc*N2;
    const float* I1 = A4 + PS2   + (size_t)bc*N2;
    const float* I2 = A4 + 2*PS2 + (size_t)bc*N2;
    const float* I3 = A4 + 3*PS2 + (size_t)bc*N2;
    int i00 = h1*128+w1, i10 = hm*128+w1, i01 = h1*128+wm, i11 = hm*128+wm;
    float t1, t2, t3, t4;
    { float a=I0[i00], b2=I1[i00], c2=I2[i00], d2=I3[i00]; t1 = -a - b2 - c2 + d2; }
    { float a=I0[i10], b2=I1[i10], c2=I2[i10], d2=I3[i10]; t2 =  a - b2 - c2 - d2; }
    { float a=I0[i01], b2=I1[i01], c2=I2[i01], d2=I3[i01]; t3 =  a - b2 + c2 + d2; }
    { float a=I0[i11], b2=I1[i11], c2=I2[i11], d2=I3[i11]; t4 = -a - b2 + c2 - d2; }
    float y00 = 0.125f*(-t1 + t2 + t3 + t4);
    float y01 = 0.125f*(-t1 - t2 + t3 - t4);
    float y10 = 0.125f*(-t1 + t2 - t3 - t4);
    float y11 = 0.125f*( t1 + t2 + t3 - t4);
    float* ob = out + (size_t)bc * N1;
    int oy = h1*2, ox = w1*2;
    ob[(size_t)oy*256 + ox]       = y00;
    ob[(size_t)oy*256 + ox + 1]   = y01;
    ob[(size_t)(oy+1)*256 + ox]   = y10;
    ob[(size_t)(oy+1)*256 + ox+1] = y11;
}

// ---------------- gfm: channel stats ----------------
__global__ __launch_bounds__(256) void k_chstat(const float* __restrict__ b1, const float* __restrict__ b2,
                         float* __restrict__ avg, float* __restrict__ mxo)
{
    int bc = blockIdx.x;            // 0..BB*96-1
    int b = bc / 96, ch = bc % 96;
    const float* src = ch < 48 ? b1 + ((size_t)b*CC + ch)*N1
                               : b2 + ((size_t)b*CC + (ch-48))*N1;
    float s = 0.f, m = -1e30f;
    for (int n = threadIdx.x; n < N1; n += 256) {
        float v = src[n]; s += v; m = fmaxf(m, v);
    }
    int lane = threadIdx.x & 63, wave = threadIdx.x >> 6;
    __shared__ float rs[4], rm[4];
#pragma unroll
    for (int off = 32; off > 0; off >>= 1) {
        s += __shfl_down(s, off);
        m = fmaxf(m, __shfl_down(m, off));
    }
    if (lane == 0) { rs[wave] = s; rm[wave] = m; }
    __syncthreads();
    if (threadIdx.x == 0) {
        float ss = rs[0]+rs[1]+rs[2]+rs[3];
        float mm = fmaxf(fmaxf(rm[0],rm[1]), fmaxf(rm[2],rm[3]));
        avg[bc] = ss * (1.0f/N1);
        mxo[bc] = mm;
    }
}

// ---------------- gfm: channel attention MLP ----------------
__global__ void k_cw(const float* __restrict__ avg, const float* __restrict__ mx,
                     const float* __restrict__ w1, const float* __restrict__ w2,
                     float* __restrict__ cw)
{
    int t = threadIdx.x;
    if (t >= BB*96) return;
    int b = t / 96, o = t % 96;
    float ta[6], tm[6];
#pragma unroll
    for (int j = 0; j < 6; ++j) {
        float sa = 0.f, sm = 0.f;
        for (int i = 0; i < 96; ++i) {
            float w = w1[j*96+i];
            sa = fmaf(w, avg[b*96+i], sa);
            sm = fmaf(w, mx[b*96+i], sm);
        }
        ta[j] = sa > 0.f ? sa : 0.f;
        tm[j] = sm > 0.f ? sm : 0.f;
    }
    float ua = 0.f, um = 0.f;
#pragma unroll
    for (int j = 0; j < 6; ++j) {
        ua = fmaf(w2[o*6+j], ta[j], ua);
        um = fmaf(w2[o*6+j], tm[j], um);
    }
    float z = ua + um;
    cw[t] = 1.0f/(1.0f+expf(-z));
}

// ---------------- gfm: weighted combine + spatial stats ----------------
__global__ __launch_bounds__(256) void k_gfm_out(const float* __restrict__ b1, const float* __restrict__ b2,
                          const float* __restrict__ cw, float* __restrict__ ob,
                          float* __restrict__ savg, float* __restrict__ smax)
{
    int g = blockIdx.x*256 + threadIdx.x;   // BB*N1
    int b = g >> 16, p = g & (N1-1);
    float s = 0.f, m = -1e30f;
#pragma unroll
    for (int c = 0; c < CC; ++c) {
        size_t idx = ((size_t)b*CC + c)*N1 + p;
        float o = cw[b*96 + c]*b1[idx] + cw[b*96 + 48 + c]*b2[idx];
        ob[idx] = o;
        s += o; m = fmaxf(m, o);
    }
    savg[(size_t)b*N1 + p] = s*(1.0f/CC);
    smax[(size_t)b*N1 + p] = m;
}

// ---------------- gfm: 7x7 spatial attention + final multiply ----------------
__global__ __launch_bounds__(256) void k_final(const float* __restrict__ savg, const float* __restrict__ smax,
                        const float* __restrict__ saw, const float* __restrict__ sab,
                        const float* __restrict__ ob, float* __restrict__ out)
{
    int g = blockIdx.x*256 + threadIdx.x;
    int b = g >> 16, p = g & (N1-1);
    int y = p >> 8, x = p & 255;
    float s = sab[0];
    const float* av = savg + (size_t)b*N1;
    const float* mx = smax + (size_t)b*N1;
#pragma unroll
    for (int ky = 0; ky < 7; ++ky) {
        int yy = y + ky - 3;
        bool yok = (yy >= 0) && (yy < 256);
        int yc = yy < 0 ? 0 : (yy > 255 ? 255 : yy);
#pragma unroll
        for (int kx = 0; kx < 7; ++kx) {
            int xx = x + kx - 3;
            bool ok = yok && (xx >= 0) && (xx < 256);
            int xc = xx < 0 ? 0 : (xx > 255 ? 255 : xx);
            int idx = yc*256 + xc;
            float a = av[idx], m2 = mx[idx];
            s = fmaf(ok ? a  : 0.f, saw[ky*7+kx], s);
            s = fmaf(ok ? m2 : 0.f, saw[49 + ky*7+kx], s);
        }
    }
    float sig = 1.0f/(1.0f+expf(-s));
#pragma unroll
    for (int c = 0; c < CC; ++c) {
        size_t idx = ((size_t)b*CC + c)*N1 + p;
        out[idx] = sig * ob[idx];
    }
}

} // anonymous namespace

extern "C" void kernel_launch(void* const* d_in, const int* in_sizes, int n_in,
                              void* d_out, int out_size, void* d_ws, size_t ws_size,
                              hipStream_t stream)
{
    const float* x    = (const float*)d_in[0];
    const float* ln1w = (const float*)d_in[1];
    const float* ln1b = (const float*)d_in[2];
    const float* temp = (const float*)d_in[3];
    const float* qkvw = (const float*)d_in[4];
    const float* qkvdw= (const float*)d_in[5];
    const float* projw= (const float*)d_in[6];
    const float* ln2w = (const float*)d_in[7];
    const float* ln2b = (const float*)d_in[8];
    const float* pinw = (const float*)d_in[9];
    const float* ffdw = (const float*)d_in[10];
    const float* poutw= (const float*)d_in[11];
    const float* caw1 = (const float*)d_in[12];
    const float* caw2 = (const float*)d_in[13];
    const float* saw  = (const float*)d_in[14];
    const float* sab  = (const float*)d_in[15];

    float* wsf  = (float*)d_ws;
    float* A4   = wsf;                               // 4 planes of (B,C,128,128)
    float* br1  = A4 + 4*PS2;
    float* br2  = br1 + NB1;
    float* x1b  = br2 + NB1;                         // tblock x1 / gfm out buffer
    float* tbA  = x1b + NB1;
    float* qkv  = tbA + PS2;                         // also pin_out (extends into qkvd)
    float* qkvd = qkv + (size_t)BB*QKVC*N1;
    float* stats= qkvd + (size_t)BB*QKVC*N1;
    float* savg = stats + 4096;
    float* smax = savg + (size_t)BB*N1;

    auto tb = [&](const float* Xin, float* outp, int Hs, int Ws) {
        int Ns = Hs*Ws;
        int npix = BB*Ns;
        k_zero<<<3, 256, 0, stream>>>(stats, 768);
        dim3 g1(npix/256, QKVC/16);
        k_ln_conv<QKVC><<<g1, 256, 0, stream>>>(Xin, ln1w, ln1b, qkvw, qkv, Ns);
        k_dw3<<<(BB*QKVC*Ns)/256, 256, 0, stream>>>(qkv, qkvdw, qkvd, QKVC, Hs, Ws);
        k_qk_stats<<<BB*NHEAD*32, 256, 0, stream>>>(qkvd, stats, Ns);
        k_attn<<<1, 64, 0, stream>>>(stats, temp, stats + 768);
        k_av_proj<<<npix/256, 256, 0, stream>>>(qkvd, stats + 768, projw, Xin, x1b, Ns);
        dim3 g5(npix/256, (PINC+15)/16);
        k_ln_conv<PINC><<<g5, 256, 0, stream>>>(x1b, ln2w, ln2b, pinw, qkv, Ns);
        k_ffn<<<npix/256, 256, 0, stream>>>(qkv, ffdw, poutw, x1b, outp, Hs, Ws);
    };

    tb(x, br1, 256, 256);
    k_nlwt<<<(BB*CC*N2)/256, 256, 0, stream>>>(x, A4);
    tb(A4, tbA, 128, 128);
    k_inlwt<<<(BB*CC*N2)/256, 256, 0, stream>>>(tbA, A4, br2);
    k_chstat<<<BB*96, 256, 0, stream>>>(br1, br2, stats + 1344, stats + 1536);
    k_cw<<<1, 256, 0, stream>>>(stats + 1344, stats + 1536, caw1, caw2, stats + 1728);
    k_gfm_out<<<(BB*N1)/256, 256, 0, stream>>>(br1, br2, stats + 1728, x1b, savg, smax);
    k_final<<<(BB*N1)/256, 256, 0, stream>>>(savg, smax, saw, sab, x1b, (float*)d_out);
}

// Round 2
// 873.157 us; speedup vs baseline: 1.1507x; 1.1507x over previous
//
#include <hip/hip_runtime.h>
#include <math.h>

namespace {

constexpr int BB   = 2;
constexpr int CC   = 48;
constexpr int NHEAD= 8;
constexpr int CPH  = 6;     // channels per head
constexpr int HID  = 127;   // int(48*2.66)
constexpr int QKVC = 144;
constexpr int PINC = 254;
constexpr int N1   = 256*256;
constexpr int N2   = 128*128;
constexpr size_t PS2 = (size_t)BB*CC*N2;   // one nlwt plane
constexpr size_t NB1 = (size_t)BB*CC*N1;

// stats layout (floats, relative to stats base):
// [0,96)    q sum-sq      (b*48 + ch)
// [96,192)  k sum-sq
// [192,768) gram          ((b*8+h)*36 + c*6+d)
// [768,1344) attn weights ((b*8+h)*36 + c*6+d)
// [1344,1536) gfm channel avg (b*96+ch)
// [1536,1728) gfm channel max
// [1728,1920) gfm cw

__device__ __forceinline__ float geluf(float x) {
    return 0.5f * x * (1.0f + erff(x * 0.70710678118654752440f));
}

__device__ __forceinline__ float b2f(unsigned short u) {
    unsigned int x = ((unsigned int)u) << 16;
    float f; __builtin_memcpy(&f, &x, 4); return f;
}
__device__ __forceinline__ unsigned short f2b(float f) {
    unsigned int x; __builtin_memcpy(&x, &f, 4);
    unsigned int r = (x + 0x7FFFu + ((x >> 16) & 1u)) >> 16;   // RNE
    return (unsigned short)r;
}

__global__ void k_zero(float* __restrict__ p, int n)
{
    int i = blockIdx.x*256 + threadIdx.x;
    if (i < n) p[i] = 0.f;
}

// ---------------- LN (channel) + 1x1 conv ----------------
template<int CHUNK, bool BF16OUT>
__device__ __forceinline__ void conv_chunk(const float* __restrict__ Wt, int ocb,
                                           const float (&xv)[CC], void* __restrict__ obv,
                                           int Ns)
{
    float acc[CHUNK];
#pragma unroll
    for (int i = 0; i < CHUNK; ++i) acc[i] = 0.f;
#pragma unroll
    for (int c = 0; c < CC; ++c) {
        float xc = xv[c];
#pragma unroll
        for (int i = 0; i < CHUNK; ++i)
            acc[i] = fmaf(xc, Wt[(ocb + i) * CC + c], acc[i]);
    }
    if (BF16OUT) {
        unsigned short* ob = (unsigned short*)obv;
#pragma unroll
        for (int i = 0; i < CHUNK; ++i) ob[(size_t)(ocb + i) * Ns] = f2b(acc[i]);
    } else {
        float* ob = (float*)obv;
#pragma unroll
        for (int i = 0; i < CHUNK; ++i) ob[(size_t)(ocb + i) * Ns] = acc[i];
    }
}

template<int OC, bool BF16OUT>
__global__ __launch_bounds__(256) void k_ln_conv(const float* __restrict__ X,
                       const float* __restrict__ lw, const float* __restrict__ lb,
                       const float* __restrict__ Wt, void* __restrict__ out, int Ns)
{
    int g = blockIdx.x * 256 + threadIdx.x;
    int b = g / Ns, p = g - b * Ns;
    int ocb = blockIdx.y * 16;
    const float* xb = X + (size_t)b * CC * Ns + p;
    float xv[CC];
    float s = 0.f, s2 = 0.f;
#pragma unroll
    for (int c = 0; c < CC; ++c) {
        float v = xb[(size_t)c * Ns];
        xv[c] = v; s += v; s2 += v * v;
    }
    float mu  = s * (1.0f / CC);
    float var = s2 * (1.0f / CC) - mu * mu;
    float inv = 1.0f / sqrtf(var + 1e-5f);
#pragma unroll
    for (int c = 0; c < CC; ++c)
        xv[c] = (xv[c] - mu) * inv * lw[c] + lb[c];
    char* ob = (char*)out + ((size_t)b * OC * Ns + p) * (BF16OUT ? 2 : 4);
    constexpr int R = (OC % 16 == 0) ? 16 : (OC % 16);
    if (ocb + 16 <= OC) conv_chunk<16, BF16OUT>(Wt, ocb, xv, ob - (size_t)0, Ns);
    else                conv_chunk<R, BF16OUT>(Wt, ocb, xv, ob, Ns);
}

// ---------------- depthwise 3x3 (zero pad), fp32 in/out ----------------
__global__ __launch_bounds__(256) void k_dw3(const float* __restrict__ in, const float* __restrict__ w,
                      float* __restrict__ out, int nch, int Hs, int Ws)
{
    int Ns = Hs * Ws;
    int g = blockIdx.x * 256 + threadIdx.x;
    int p = g % Ns, bc = g / Ns;
    int c = bc % nch;
    int y = p / Ws, x = p - y * Ws;
    const float* ip = in + (size_t)bc * Ns;
    const float* wc = w + c * 9;
    float s = 0.f;
#pragma unroll
    for (int ky = 0; ky < 3; ++ky) {
        int yy = y + ky - 1;
        bool yok = (yy >= 0) && (yy < Hs);
        int yc = yy < 0 ? 0 : (yy >= Hs ? Hs - 1 : yy);
#pragma unroll
        for (int kx = 0; kx < 3; ++kx) {
            int xx = x + kx - 1;
            bool ok = yok && (xx >= 0) && (xx < Ws);
            int xc = xx < 0 ? 0 : (xx >= Ws ? Ws - 1 : xx);
            float v = ip[(size_t)yc * Ws + xc];
            s = fmaf(ok ? v : 0.f, wc[ky * 3 + kx], s);
        }
    }
    out[(size_t)bc * Ns + p] = s;
}

// ---------------- q/k norms + gram reduction ----------------
__global__ __launch_bounds__(256) void k_qk_stats(const float* __restrict__ qkvd,
                                                  float* __restrict__ st, int Ns)
{
    const int NBLK = 32;
    int bh = blockIdx.x / NBLK, blk = blockIdx.x % NBLK;
    int b = bh / NHEAD, h = bh % NHEAD;
    const float* qb = qkvd + ((size_t)b*QKVC + h*CPH)*Ns;
    const float* kb = qkvd + ((size_t)b*QKVC + 48 + h*CPH)*Ns;
    float vals[48];
#pragma unroll
    for (int i = 0; i < 48; ++i) vals[i] = 0.f;
    for (int n = blk*256 + (int)threadIdx.x; n < Ns; n += NBLK*256) {
        float qv[CPH], kv[CPH];
#pragma unroll
        for (int i = 0; i < CPH; ++i) { qv[i] = qb[(size_t)i*Ns + n]; kv[i] = kb[(size_t)i*Ns + n]; }
#pragma unroll
        for (int i = 0; i < CPH; ++i) {
            vals[i]   = fmaf(qv[i], qv[i], vals[i]);
            vals[6+i] = fmaf(kv[i], kv[i], vals[6+i]);
        }
#pragma unroll
        for (int i = 0; i < CPH; ++i)
#pragma unroll
            for (int j = 0; j < CPH; ++j)
                vals[12 + i*6 + j] = fmaf(qv[i], kv[j], vals[12 + i*6 + j]);
    }
    __shared__ float red[4][48];
    int lane = threadIdx.x & 63, wave = threadIdx.x >> 6;
#pragma unroll
    for (int i = 0; i < 48; ++i) {
        float v = vals[i];
#pragma unroll
        for (int off = 32; off > 0; off >>= 1) v += __shfl_down(v, off);
        if (lane == 0) red[wave][i] = v;
    }
    __syncthreads();
    if ((int)threadIdx.x < 48) {
        int i = threadIdx.x;
        float v = red[0][i] + red[1][i] + red[2][i] + red[3][i];
        float* dst;
        if (i < 6)       dst = st + b*48 + h*CPH + i;
        else if (i < 12) dst = st + 96 + b*48 + h*CPH + (i-6);
        else             dst = st + 192 + (b*NHEAD+h)*36 + (i-12);
        atomicAdd(dst, v);
    }
}

// ---------------- tiny softmax over 6x6 per (b,h) ----------------
__global__ void k_attn(const float* __restrict__ st, const float* __restrict__ temp,
                       float* __restrict__ ao)
{
    int t = threadIdx.x;
    if (t >= BB*NHEAD) return;
    int b = t / NHEAD, h = t % NHEAD;
    const float* sqq = st + b*48 + h*CPH;
    const float* sqk = st + 96 + b*48 + h*CPH;
    const float* g   = st + 192 + (b*NHEAD+h)*36;
    float T = temp[h];
    float nq[CPH], nk[CPH];
#pragma unroll
    for (int i = 0; i < CPH; ++i) {
        nq[i] = fmaxf(sqrtf(sqq[i]), 1e-12f);
        nk[i] = fmaxf(sqrtf(sqk[i]), 1e-12f);
    }
    float* out = ao + (b*NHEAD+h)*36;
#pragma unroll
    for (int c = 0; c < CPH; ++c) {
        float l[CPH]; float m = -1e30f;
#pragma unroll
        for (int d = 0; d < CPH; ++d) {
            l[d] = g[c*6+d] / (nq[c]*nk[d]) * T;
            m = fmaxf(m, l[d]);
        }
        float ssum = 0.f;
#pragma unroll
        for (int d = 0; d < CPH; ++d) { l[d] = expf(l[d]-m); ssum += l[d]; }
        float r = 1.0f/ssum;
#pragma unroll
        for (int d = 0; d < CPH; ++d) out[c*6+d] = l[d]*r;
    }
}

// ---------------- attn @ v + proj 1x1 + residual (16-oc chunks) ----------------
__global__ __launch_bounds__(256) void k_av_proj(const float* __restrict__ qkvd, const float* __restrict__ attn,
                          const float* __restrict__ projw, const float* __restrict__ X,
                          float* __restrict__ x1, int Ns)
{
    int g = blockIdx.x*256 + threadIdx.x;
    int b = g / Ns, p = g - b*Ns;
    int ocb = blockIdx.y * 16;
    const float* vb = qkvd + ((size_t)b*QKVC + 96)*Ns + p;
    float vv[CC];
#pragma unroll
    for (int c = 0; c < CC; ++c) vv[c] = vb[(size_t)c*Ns];
    const float* at = attn + b*288;
    float o[CC];
#pragma unroll
    for (int h = 0; h < NHEAD; ++h)
#pragma unroll
        for (int cc = 0; cc < CPH; ++cc) {
            float acc = 0.f;
#pragma unroll
            for (int d = 0; d < CPH; ++d)
                acc = fmaf(at[(h*CPH+cc)*CPH + d], vv[h*CPH + d], acc);
            o[h*CPH+cc] = acc;
        }
    const float* xb = X + (size_t)b*CC*Ns + p;
    float* ob = x1 + (size_t)b*CC*Ns + p;
    float acc[16];
#pragma unroll
    for (int i = 0; i < 16; ++i) acc[i] = 0.f;
#pragma unroll
    for (int c = 0; c < CC; ++c) {
#pragma unroll
        for (int i = 0; i < 16; ++i)
            acc[i] = fmaf(o[c], projw[(ocb+i)*CC + c], acc[i]);
    }
#pragma unroll
    for (int i = 0; i < 16; ++i)
        ob[(size_t)(ocb+i)*Ns] = xb[(size_t)(ocb+i)*Ns] + acc[i];
}

// ---------------- ffn part 1: dw3x3 (bf16 in) + gelu gate -> bf16 ----------------
__device__ __forceinline__ float dw9b(const unsigned short* __restrict__ plane,
                                      const float* __restrict__ w9,
                                      int y, int x, int Hs, int Ws)
{
    float s = 0.f;
#pragma unroll
    for (int ky = 0; ky < 3; ++ky) {
        int yy = y + ky - 1;
        bool yok = (yy >= 0) && (yy < Hs);
        int yc = yy < 0 ? 0 : (yy >= Hs ? Hs-1 : yy);
#pragma unroll
        for (int kx = 0; kx < 3; ++kx) {
            int xx = x + kx - 1;
            bool ok = yok && (xx >= 0) && (xx < Ws);
            int xc = xx < 0 ? 0 : (xx >= Ws ? Ws-1 : xx);
            float v = b2f(plane[(size_t)yc*Ws + xc]);
            s = fmaf(ok ? v : 0.f, w9[ky*3+kx], s);
        }
    }
    return s;
}

__global__ __launch_bounds__(256) void k_dwgate(const unsigned short* __restrict__ pin,
                         const float* __restrict__ dww,
                         unsigned short* __restrict__ gate, int Hs, int Ws)
{
    int Ns = Hs*Ws;
    int g = blockIdx.x*256 + threadIdx.x;     // over BB*HID*Ns
    int p = g % Ns, bc = g / Ns;
    int b = bc / HID, c = bc - b*HID;
    int y = p / Ws, x = p - y*Ws;
    const unsigned short* p1 = pin + ((size_t)b*PINC + c)*Ns;
    const unsigned short* p2 = pin + ((size_t)b*PINC + HID + c)*Ns;
    float d1 = dw9b(p1, dww + c*9,        y, x, Hs, Ws);
    float d2 = dw9b(p2, dww + (c+HID)*9,  y, x, Hs, Ws);
    gate[(size_t)bc*Ns + p] = f2b(geluf(d1) * d2);
}

// ---------------- ffn part 2: 1x1 conv 127->48 + residual ----------------
__global__ __launch_bounds__(256) void k_pout(const unsigned short* __restrict__ gate,
                       const float* __restrict__ poutw, const float* __restrict__ x1,
                       float* __restrict__ out, int Ns)
{
    int g = blockIdx.x*256 + threadIdx.x;
    int b = g / Ns, p = g - b*Ns;
    int ocb = blockIdx.y * 16;
    const unsigned short* gb = gate + (size_t)b*HID*Ns + p;
    float acc[16];
#pragma unroll
    for (int i = 0; i < 16; ++i) acc[i] = 0.f;
    for (int c = 0; c < HID; ++c) {
        float tv = b2f(gb[(size_t)c*Ns]);
#pragma unroll
        for (int i = 0; i < 16; ++i)
            acc[i] = fmaf(tv, poutw[(ocb+i)*HID + c], acc[i]);
    }
    const float* xb = x1 + (size_t)b*CC*Ns + p;
    float* ob = out + (size_t)b*CC*Ns + p;
#pragma unroll
    for (int i = 0; i < 16; ++i)
        ob[(size_t)(ocb+i)*Ns] = xb[(size_t)(ocb+i)*Ns] + acc[i];
}

// ---------------- nlwt ----------------
__global__ __launch_bounds__(256) void k_nlwt(const float* __restrict__ X, float* __restrict__ A4)
{
    int g = blockIdx.x*256 + threadIdx.x;   // over BB*CC*N2
    int n = g & (N2-1); int bc = g >> 14;
    int h1 = n >> 7, w1 = n & 127;
    int hb = (h1+1)&127, wb = (w1+1)&127;
    const float* xp = X + (size_t)bc * N1;
    float t1, t2, t3, t4;
    {
        int y=h1, z=w1;
        float c0=xp[(2*y)*256+2*z], c1=xp[(2*y)*256+2*z+1], c2=xp[(2*y+1)*256+2*z], c3=xp[(2*y+1)*256+2*z+1];
        t1 = 0.5f*(-c0 - c1 - c2 + c3);
    }
    {
        int y=hb, z=w1;
        float c0=xp[(2*y)*256+2*z], c1=xp[(2*y)*256+2*z+1], c2=xp[(2*y+1)*256+2*z], c3=xp[(2*y+1)*256+2*z+1];
        t2 = 0.5f*( c0 - c1 + c2 + c3);
    }
    {
        int y=h1, z=wb;
        float c0=xp[(2*y)*256+2*z], c1=xp[(2*y)*256+2*z+1], c2=xp[(2*y+1)*256+2*z], c3=xp[(2*y+1)*256+2*z+1];
        t3 = 0.5f*( c0 + c1 - c2 + c3);
    }
    {
        int y=hb, z=wb;
        float c0=xp[(2*y)*256+2*z], c1=xp[(2*y)*256+2*z+1], c2=xp[(2*y+1)*256+2*z], c3=xp[(2*y+1)*256+2*z+1];
        t4 = 0.5f*( c0 - c1 - c2 - c3);
    }
    size_t o = (size_t)bc*N2 + n;
    A4[o]           = -t1 + t2 + t3 - t4;
    A4[PS2 + o]     = -t1 - t2 - t3 - t4;
    A4[2*PS2 + o]   = -t1 - t2 + t3 + t4;
    A4[3*PS2 + o]   =  t1 - t2 + t3 - t4;
}

// ---------------- inlwt ----------------
__global__ __launch_bounds__(256) void k_inlwt(const float* __restrict__ Ain, const float* __restrict__ A4,
                        float* __restrict__ out)
{
    int g = blockIdx.x*256 + threadIdx.x;   // over BB*CC*N2
    int n = g & (N2-1); int bc = g >> 14;
    int h1 = n >> 7, w1 = n & 127;
    int hm = (h1-1)&127, wm = (w1-1)&127;
    const float* I0 = Ain + (size_t)bc*N2;
    const float* I1 = A4 + PS2   + (size_t)bc*N2;
    const float* I2 = A4 + 2*PS2 + (size_t)bc*N2;
    const float* I3 = A4 + 3*PS2 + (size_t)bc*N2;
    int i00 = h1*128+w1, i10 = hm*128+w1, i01 = h1*128+wm, i11 = hm*128+wm;
    float t1, t2, t3, t4;
    { float a=I0[i00], b2=I1[i00], c2=I2[i00], d2=I3[i00]; t1 = -a - b2 - c2 + d2; }
    { float a=I0[i10], b2=I1[i10], c2=I2[i10], d2=I3[i10]; t2 =  a - b2 - c2 - d2; }
    { float a=I0[i01], b2=I1[i01], c2=I2[i01], d2=I3[i01]; t3 =  a - b2 + c2 + d2; }
    { float a=I0[i11], b2=I1[i11], c2=I2[i11], d2=I3[i11]; t4 = -a - b2 + c2 - d2; }
    float y00 = 0.125f*(-t1 + t2 + t3 + t4);
    float y01 = 0.125f*(-t1 - t2 + t3 - t4);
    float y10 = 0.125f*(-t1 + t2 - t3 - t4);
    float y11 = 0.125f*( t1 + t2 + t3 - t4);
    float* ob = out + (size_t)bc * N1;
    int oy = h1*2, ox = w1*2;
    ob[(size_t)oy*256 + ox]       = y00;
    ob[(size_t)oy*256 + ox + 1]   = y01;
    ob[(size_t)(oy+1)*256 + ox]   = y10;
    ob[(size_t)(oy+1)*256 + ox+1] = y11;
}

// ---------------- gfm: channel stats ----------------
__global__ __launch_bounds__(256) void k_chstat(const float* __restrict__ b1, const float* __restrict__ b2,
                         float* __restrict__ avg, float* __restrict__ mxo)
{
    int bc = blockIdx.x;            // 0..BB*96-1
    int b = bc / 96, ch = bc % 96;
    const float* src = ch < 48 ? b1 + ((size_t)b*CC + ch)*N1
                               : b2 + ((size_t)b*CC + (ch-48))*N1;
    float s = 0.f, m = -1e30f;
    for (int n = threadIdx.x; n < N1; n += 256) {
        float v = src[n]; s += v; m = fmaxf(m, v);
    }
    int lane = threadIdx.x & 63, wave = threadIdx.x >> 6;
    __shared__ float rs[4], rm[4];
#pragma unroll
    for (int off = 32; off > 0; off >>= 1) {
        s += __shfl_down(s, off);
        m = fmaxf(m, __shfl_down(m, off));
    }
    if (lane == 0) { rs[wave] = s; rm[wave] = m; }
    __syncthreads();
    if (threadIdx.x == 0) {
        float ss = rs[0]+rs[1]+rs[2]+rs[3];
        float mm = fmaxf(fmaxf(rm[0],rm[1]), fmaxf(rm[2],rm[3]));
        avg[bc] = ss * (1.0f/N1);
        mxo[bc] = mm;
    }
}

// ---------------- gfm: channel attention MLP ----------------
__global__ void k_cw(const float* __restrict__ avg, const float* __restrict__ mx,
                     const float* __restrict__ w1, const float* __restrict__ w2,
                     float* __restrict__ cw)
{
    int t = threadIdx.x;
    if (t >= BB*96) return;
    int b = t / 96, o = t % 96;
    float ta[6], tm[6];
#pragma unroll
    for (int j = 0; j < 6; ++j) {
        float sa = 0.f, sm = 0.f;
        for (int i = 0; i < 96; ++i) {
            float w = w1[j*96+i];
            sa = fmaf(w, avg[b*96+i], sa);
            sm = fmaf(w, mx[b*96+i], sm);
        }
        ta[j] = sa > 0.f ? sa : 0.f;
        tm[j] = sm > 0.f ? sm : 0.f;
    }
    float ua = 0.f, um = 0.f;
#pragma unroll
    for (int j = 0; j < 6; ++j) {
        ua = fmaf(w2[o*6+j], ta[j], ua);
        um = fmaf(w2[o*6+j], tm[j], um);
    }
    float z = ua + um;
    cw[t] = 1.0f/(1.0f+expf(-z));
}

// ---------------- gfm: weighted combine + spatial stats ----------------
__global__ __launch_bounds__(256) void k_gfm_out(const float* __restrict__ b1, const float* __restrict__ b2,
                          const float* __restrict__ cw, float* __restrict__ ob,
                          float* __restrict__ savg, float* __restrict__ smax)
{
    int g = blockIdx.x*256 + threadIdx.x;   // BB*N1
    int b = g >> 16, p = g & (N1-1);
    float s = 0.f, m = -1e30f;
#pragma unroll
    for (int c = 0; c < CC; ++c) {
        size_t idx = ((size_t)b*CC + c)*N1 + p;
        float o = cw[b*96 + c]*b1[idx] + cw[b*96 + 48 + c]*b2[idx];
        ob[idx] = o;
        s += o; m = fmaxf(m, o);
    }
    savg[(size_t)b*N1 + p] = s*(1.0f/CC);
    smax[(size_t)b*N1 + p] = m;
}

// ---------------- gfm: 7x7 spatial attention + final multiply ----------------
__global__ __launch_bounds__(256) void k_final(const float* __restrict__ savg, const float* __restrict__ smax,
                        const float* __restrict__ saw, const float* __restrict__ sab,
                        const float* __restrict__ ob, float* __restrict__ out)
{
    int g = blockIdx.x*256 + threadIdx.x;
    int b = g >> 16, p = g & (N1-1);
    int y = p >> 8, x = p & 255;
    float s = sab[0];
    const float* av = savg + (size_t)b*N1;
    const float* mx = smax + (size_t)b*N1;
#pragma unroll
    for (int ky = 0; ky < 7; ++ky) {
        int yy = y + ky - 3;
        bool yok = (yy >= 0) && (yy < 256);
        int yc = yy < 0 ? 0 : (yy > 255 ? 255 : yy);
#pragma unroll
        for (int kx = 0; kx < 7; ++kx) {
            int xx = x + kx - 3;
            bool ok = yok && (xx >= 0) && (xx < 256);
            int xc = xx < 0 ? 0 : (xx > 255 ? 255 : xx);
            int idx = yc*256 + xc;
            float a = av[idx], m2 = mx[idx];
            s = fmaf(ok ? a  : 0.f, saw[ky*7+kx], s);
            s = fmaf(ok ? m2 : 0.f, saw[49 + ky*7+kx], s);
        }
    }
    float sig = 1.0f/(1.0f+expf(-s));
#pragma unroll
    for (int c = 0; c < CC; ++c) {
        size_t idx = ((size_t)b*CC + c)*N1 + p;
        out[idx] = sig * ob[idx];
    }
}

} // anonymous namespace

extern "C" void kernel_launch(void* const* d_in, const int* in_sizes, int n_in,
                              void* d_out, int out_size, void* d_ws, size_t ws_size,
                              hipStream_t stream)
{
    const float* x    = (const float*)d_in[0];
    const float* ln1w = (const float*)d_in[1];
    const float* ln1b = (const float*)d_in[2];
    const float* temp = (const float*)d_in[3];
    const float* qkvw = (const float*)d_in[4];
    const float* qkvdw= (const float*)d_in[5];
    const float* projw= (const float*)d_in[6];
    const float* ln2w = (const float*)d_in[7];
    const float* ln2b = (const float*)d_in[8];
    const float* pinw = (const float*)d_in[9];
    const float* ffdw = (const float*)d_in[10];
    const float* poutw= (const float*)d_in[11];
    const float* caw1 = (const float*)d_in[12];
    const float* caw2 = (const float*)d_in[13];
    const float* saw  = (const float*)d_in[14];
    const float* sab  = (const float*)d_in[15];

    float* wsf  = (float*)d_ws;
    float* A4   = wsf;                               // 4 planes of (B,C,128,128)
    float* br1  = A4 + 4*PS2;
    float* br2  = br1 + NB1;
    float* x1b  = br2 + NB1;                         // tblock x1 / gfm out buffer
    float* tbA  = x1b + NB1;
    float* qkv  = tbA + PS2;                         // fp32 qkv conv out; bf16 pin_out
    float* qkvd = qkv + (size_t)BB*QKVC*N1;          // fp32 dwconv out; bf16 gate
    float* stats= qkvd + (size_t)BB*QKVC*N1;
    float* savg = stats + 4096;
    float* smax = savg + (size_t)BB*N1;

    auto tb = [&](const float* Xin, float* outp, int Hs, int Ws) {
        int Ns = Hs*Ws;
        int npix = BB*Ns;
        k_zero<<<3, 256, 0, stream>>>(stats, 768);
        dim3 g1(npix/256, QKVC/16);
        k_ln_conv<QKVC, false><<<g1, 256, 0, stream>>>(Xin, ln1w, ln1b, qkvw, qkv, Ns);
        k_dw3<<<(BB*QKVC*Ns)/256, 256, 0, stream>>>(qkv, qkvdw, qkvd, QKVC, Hs, Ws);
        k_qk_stats<<<BB*NHEAD*32, 256, 0, stream>>>(qkvd, stats, Ns);
        k_attn<<<1, 64, 0, stream>>>(stats, temp, stats + 768);
        dim3 g4(npix/256, 3);
        k_av_proj<<<g4, 256, 0, stream>>>(qkvd, stats + 768, projw, Xin, x1b, Ns);
        dim3 g5(npix/256, (PINC+15)/16);
        k_ln_conv<PINC, true><<<g5, 256, 0, stream>>>(x1b, ln2w, ln2b, pinw, qkv, Ns);
        k_dwgate<<<(BB*HID*Ns)/256, 256, 0, stream>>>((const unsigned short*)qkv, ffdw,
                                                      (unsigned short*)qkvd, Hs, Ws);
        dim3 g6(npix/256, 3);
        k_pout<<<g6, 256, 0, stream>>>((const unsigned short*)qkvd, poutw, x1b, outp, Ns);
    };

    tb(x, br1, 256, 256);
    k_nlwt<<<(BB*CC*N2)/256, 256, 0, stream>>>(x, A4);
    tb(A4, tbA, 128, 128);
    k_inlwt<<<(BB*CC*N2)/256, 256, 0, stream>>>(tbA, A4, br2);
    k_chstat<<<BB*96, 256, 0, stream>>>(br1, br2, stats + 1344, stats + 1536);
    k_cw<<<1, 256, 0, stream>>>(stats + 1344, stats + 1536, caw1, caw2, stats + 1728);
    k_gfm_out<<<(BB*N1)/256, 256, 0, stream>>>(br1, br2, stats + 1728, x1b, savg, smax);
    k_final<<<(BB*N1)/256, 256, 0, stream>>>(savg, smax, saw, sab, x1b, (float*)d_out);
}

// Round 3
// 721.866 us; speedup vs baseline: 1.3918x; 1.2096x over previous
//
#include <hip/hip_runtime.h>
#include <math.h>

namespace {

constexpr int BB   = 2;
constexpr int CC   = 48;
constexpr int NHEAD= 8;
constexpr int CPH  = 6;     // channels per head
constexpr int HID  = 127;   // int(48*2.66)
constexpr int QKVC = 144;
constexpr int PINC = 254;
constexpr int N1   = 256*256;
constexpr int N2   = 128*128;
constexpr size_t PS2 = (size_t)BB*CC*N2;   // one nlwt plane
constexpr size_t NB1 = (size_t)BB*CC*N1;

// stats layout (floats, relative to stats base):
// [0,96)    q sum-sq      (b*48 + ch)
// [96,192)  k sum-sq
// [192,768) gram          ((b*8+h)*36 + c*6+d)
// [768,1344) attn weights ((b*8+h)*36 + c*6+d)
// [1344,1536) gfm channel avg (b*96+ch)
// [1536,1728) gfm channel max
// [1728,1920) gfm cw

__device__ __forceinline__ float geluf(float x) {
    return 0.5f * x * (1.0f + erff(x * 0.70710678118654752440f));
}

__device__ __forceinline__ float b2f(unsigned short u) {
    unsigned int x = ((unsigned int)u) << 16;
    float f; __builtin_memcpy(&f, &x, 4); return f;
}
__device__ __forceinline__ unsigned short f2b(float f) {
    unsigned int x; __builtin_memcpy(&x, &f, 4);
    unsigned int r = (x + 0x7FFFu + ((x >> 16) & 1u)) >> 16;   // RNE
    return (unsigned short)r;
}

__global__ void k_zero(float* __restrict__ p, int n)
{
    int i = blockIdx.x*256 + threadIdx.x;
    if (i < n) p[i] = 0.f;
}

// repack pout weights [oc][c] -> [c][oc] (contiguous 48 per c)
__global__ void k_repw(const float* __restrict__ w, float* __restrict__ wt)
{
    int i = blockIdx.x*256 + threadIdx.x;
    if (i < HID*48) {
        int c = i / 48, oc = i - c*48;
        wt[c*48 + oc] = w[oc*HID + c];
    }
}

// ---------------- LN (channel) + 1x1 conv ----------------
template<int CHUNK, bool BF16OUT>
__device__ __forceinline__ void conv_chunk(const float* __restrict__ Wt, int ocb,
                                           const float (&xv)[CC], void* __restrict__ obv,
                                           int Ns)
{
    float acc[CHUNK];
#pragma unroll
    for (int i = 0; i < CHUNK; ++i) acc[i] = 0.f;
#pragma unroll
    for (int c = 0; c < CC; ++c) {
        float xc = xv[c];
#pragma unroll
        for (int i = 0; i < CHUNK; ++i)
            acc[i] = fmaf(xc, Wt[(ocb + i) * CC + c], acc[i]);
    }
    if (BF16OUT) {
        unsigned short* ob = (unsigned short*)obv;
#pragma unroll
        for (int i = 0; i < CHUNK; ++i) ob[(size_t)(ocb + i) * Ns] = f2b(acc[i]);
    } else {
        float* ob = (float*)obv;
#pragma unroll
        for (int i = 0; i < CHUNK; ++i) ob[(size_t)(ocb + i) * Ns] = acc[i];
    }
}

template<int OC, bool BF16OUT>
__global__ __launch_bounds__(256) void k_ln_conv(const float* __restrict__ X,
                       const float* __restrict__ lw, const float* __restrict__ lb,
                       const float* __restrict__ Wt, void* __restrict__ out, int Ns)
{
    int g = blockIdx.x * 256 + threadIdx.x;
    int b = g / Ns, p = g - b * Ns;
    int ocb = blockIdx.y * 16;
    const float* xb = X + (size_t)b * CC * Ns + p;
    float xv[CC];
    float s = 0.f, s2 = 0.f;
#pragma unroll
    for (int c = 0; c < CC; ++c) {
        float v = xb[(size_t)c * Ns];
        xv[c] = v; s += v; s2 += v * v;
    }
    float mu  = s * (1.0f / CC);
    float var = s2 * (1.0f / CC) - mu * mu;
    float inv = 1.0f / sqrtf(var + 1e-5f);
#pragma unroll
    for (int c = 0; c < CC; ++c)
        xv[c] = (xv[c] - mu) * inv * lw[c] + lb[c];
    char* ob = (char*)out + ((size_t)b * OC * Ns + p) * (BF16OUT ? 2 : 4);
    constexpr int R = (OC % 16 == 0) ? 16 : (OC % 16);
    if (ocb + 16 <= OC) conv_chunk<16, BF16OUT>(Wt, ocb, xv, ob, Ns);
    else                conv_chunk<R, BF16OUT>(Wt, ocb, xv, ob, Ns);
}

// ---------------- depthwise 3x3 (zero pad), fp32 in/out ----------------
__global__ __launch_bounds__(256) void k_dw3(const float* __restrict__ in, const float* __restrict__ w,
                      float* __restrict__ out, int nch, int Hs, int Ws)
{
    int Ns = Hs * Ws;
    int g = blockIdx.x * 256 + threadIdx.x;
    int p = g % Ns, bc = g / Ns;
    int c = bc % nch;
    int y = p / Ws, x = p - y * Ws;
    const float* ip = in + (size_t)bc * Ns;
    const float* wc = w + c * 9;
    float s = 0.f;
#pragma unroll
    for (int ky = 0; ky < 3; ++ky) {
        int yy = y + ky - 1;
        bool yok = (yy >= 0) && (yy < Hs);
        int yc = yy < 0 ? 0 : (yy >= Hs ? Hs - 1 : yy);
#pragma unroll
        for (int kx = 0; kx < 3; ++kx) {
            int xx = x + kx - 1;
            bool ok = yok && (xx >= 0) && (xx < Ws);
            int xc = xx < 0 ? 0 : (xx >= Ws ? Ws - 1 : xx);
            float v = ip[(size_t)yc * Ws + xc];
            s = fmaf(ok ? v : 0.f, wc[ky * 3 + kx], s);
        }
    }
    out[(size_t)bc * Ns + p] = s;
}

// ---------------- q/k norms + gram reduction ----------------
__global__ __launch_bounds__(256) void k_qk_stats(const float* __restrict__ qkvd,
                                                  float* __restrict__ st, int Ns)
{
    const int NBLK = 32;
    int bh = blockIdx.x / NBLK, blk = blockIdx.x % NBLK;
    int b = bh / NHEAD, h = bh % NHEAD;
    const float* qb = qkvd + ((size_t)b*QKVC + h*CPH)*Ns;
    const float* kb = qkvd + ((size_t)b*QKVC + 48 + h*CPH)*Ns;
    float vals[48];
#pragma unroll
    for (int i = 0; i < 48; ++i) vals[i] = 0.f;
    for (int n = blk*256 + (int)threadIdx.x; n < Ns; n += NBLK*256) {
        float qv[CPH], kv[CPH];
#pragma unroll
        for (int i = 0; i < CPH; ++i) { qv[i] = qb[(size_t)i*Ns + n]; kv[i] = kb[(size_t)i*Ns + n]; }
#pragma unroll
        for (int i = 0; i < CPH; ++i) {
            vals[i]   = fmaf(qv[i], qv[i], vals[i]);
            vals[6+i] = fmaf(kv[i], kv[i], vals[6+i]);
        }
#pragma unroll
        for (int i = 0; i < CPH; ++i)
#pragma unroll
            for (int j = 0; j < CPH; ++j)
                vals[12 + i*6 + j] = fmaf(qv[i], kv[j], vals[12 + i*6 + j]);
    }
    __shared__ float red[4][48];
    int lane = threadIdx.x & 63, wave = threadIdx.x >> 6;
#pragma unroll
    for (int i = 0; i < 48; ++i) {
        float v = vals[i];
#pragma unroll
        for (int off = 32; off > 0; off >>= 1) v += __shfl_down(v, off);
        if (lane == 0) red[wave][i] = v;
    }
    __syncthreads();
    if ((int)threadIdx.x < 48) {
        int i = threadIdx.x;
        float v = red[0][i] + red[1][i] + red[2][i] + red[3][i];
        float* dst;
        if (i < 6)       dst = st + b*48 + h*CPH + i;
        else if (i < 12) dst = st + 96 + b*48 + h*CPH + (i-6);
        else             dst = st + 192 + (b*NHEAD+h)*36 + (i-12);
        atomicAdd(dst, v);
    }
}

// ---------------- tiny softmax over 6x6 per (b,h) ----------------
__global__ void k_attn(const float* __restrict__ st, const float* __restrict__ temp,
                       float* __restrict__ ao)
{
    int t = threadIdx.x;
    if (t >= BB*NHEAD) return;
    int b = t / NHEAD, h = t % NHEAD;
    const float* sqq = st + b*48 + h*CPH;
    const float* sqk = st + 96 + b*48 + h*CPH;
    const float* g   = st + 192 + (b*NHEAD+h)*36;
    float T = temp[h];
    float nq[CPH], nk[CPH];
#pragma unroll
    for (int i = 0; i < CPH; ++i) {
        nq[i] = fmaxf(sqrtf(sqq[i]), 1e-12f);
        nk[i] = fmaxf(sqrtf(sqk[i]), 1e-12f);
    }
    float* out = ao + (b*NHEAD+h)*36;
#pragma unroll
    for (int c = 0; c < CPH; ++c) {
        float l[CPH]; float m = -1e30f;
#pragma unroll
        for (int d = 0; d < CPH; ++d) {
            l[d] = g[c*6+d] / (nq[c]*nk[d]) * T;
            m = fmaxf(m, l[d]);
        }
        float ssum = 0.f;
#pragma unroll
        for (int d = 0; d < CPH; ++d) { l[d] = expf(l[d]-m); ssum += l[d]; }
        float r = 1.0f/ssum;
#pragma unroll
        for (int d = 0; d < CPH; ++d) out[c*6+d] = l[d]*r;
    }
}

// ---------------- attn @ v + proj 1x1 + residual (16-oc chunks) ----------------
__global__ __launch_bounds__(256) void k_av_proj(const float* __restrict__ qkvd, const float* __restrict__ attn,
                          const float* __restrict__ projw, const float* __restrict__ X,
                          float* __restrict__ x1, int Ns)
{
    int g = blockIdx.x*256 + threadIdx.x;
    int b = g / Ns, p = g - b*Ns;
    int ocb = blockIdx.y * 16;
    const float* vb = qkvd + ((size_t)b*QKVC + 96)*Ns + p;
    float vv[CC];
#pragma unroll
    for (int c = 0; c < CC; ++c) vv[c] = vb[(size_t)c*Ns];
    const float* at = attn + b*288;
    float o[CC];
#pragma unroll
    for (int h = 0; h < NHEAD; ++h)
#pragma unroll
        for (int cc = 0; cc < CPH; ++cc) {
            float acc = 0.f;
#pragma unroll
            for (int d = 0; d < CPH; ++d)
                acc = fmaf(at[(h*CPH+cc)*CPH + d], vv[h*CPH + d], acc);
            o[h*CPH+cc] = acc;
        }
    const float* xb = X + (size_t)b*CC*Ns + p;
    float* ob = x1 + (size_t)b*CC*Ns + p;
    float acc[16];
#pragma unroll
    for (int i = 0; i < 16; ++i) acc[i] = 0.f;
#pragma unroll
    for (int c = 0; c < CC; ++c) {
#pragma unroll
        for (int i = 0; i < 16; ++i)
            acc[i] = fmaf(o[c], projw[(ocb+i)*CC + c], acc[i]);
    }
#pragma unroll
    for (int i = 0; i < 16; ++i)
        ob[(size_t)(ocb+i)*Ns] = xb[(size_t)(ocb+i)*Ns] + acc[i];
}

// ---------------- ffn part 1: dw3x3 (bf16 in) + gelu gate -> bf16 ----------------
__device__ __forceinline__ float dw9b(const unsigned short* __restrict__ plane,
                                      const float* __restrict__ w9,
                                      int y, int x, int Hs, int Ws)
{
    float s = 0.f;
#pragma unroll
    for (int ky = 0; ky < 3; ++ky) {
        int yy = y + ky - 1;
        bool yok = (yy >= 0) && (yy < Hs);
        int yc = yy < 0 ? 0 : (yy >= Hs ? Hs-1 : yy);
#pragma unroll
        for (int kx = 0; kx < 3; ++kx) {
            int xx = x + kx - 1;
            bool ok = yok && (xx >= 0) && (xx < Ws);
            int xc = xx < 0 ? 0 : (xx >= Ws ? Ws-1 : xx);
            float v = b2f(plane[(size_t)yc*Ws + xc]);
            s = fmaf(ok ? v : 0.f, w9[ky*3+kx], s);
        }
    }
    return s;
}

__global__ __launch_bounds__(256) void k_dwgate(const unsigned short* __restrict__ pin,
                         const float* __restrict__ dww,
                         unsigned short* __restrict__ gate, int Hs, int Ws)
{
    int Ns = Hs*Ws;
    int g = blockIdx.x*256 + threadIdx.x;     // over BB*HID*Ns
    int p = g % Ns, bc = g / Ns;
    int b = bc / HID, c = bc - b*HID;
    int y = p / Ws, x = p - y*Ws;
    const unsigned short* p1 = pin + ((size_t)b*PINC + c)*Ns;
    const unsigned short* p2 = pin + ((size_t)b*PINC + HID + c)*Ns;
    float d1 = dw9b(p1, dww + c*9,        y, x, Hs, Ws);
    float d2 = dw9b(p2, dww + (c+HID)*9,  y, x, Hs, Ws);
    gate[(size_t)bc*Ns + p] = f2b(geluf(d1) * d2);
}

// ---------------- ffn part 2: 1x1 conv 127->48 + residual ----------------
// 2 pixels/thread, unroll-8 over channels, repacked weights wt[c*48+oc]
template<int U>
__device__ __forceinline__ void pout_chunk(const unsigned short* __restrict__ gb, int c0, int Ns,
                                           const float* __restrict__ wt, int ocb,
                                           float (&a0)[16], float (&a1)[16])
{
    unsigned int gv[U];
#pragma unroll
    for (int u = 0; u < U; ++u)
        gv[u] = *(const unsigned int*)(gb + (size_t)(c0+u)*Ns);
#pragma unroll
    for (int u = 0; u < U; ++u) {
        float t0 = b2f((unsigned short)(gv[u] & 0xffffu));
        float t1 = b2f((unsigned short)(gv[u] >> 16));
        const float* wr = wt + (c0+u)*48 + ocb;
#pragma unroll
        for (int i = 0; i < 16; ++i) {
            float w = wr[i];
            a0[i] = fmaf(t0, w, a0[i]);
            a1[i] = fmaf(t1, w, a1[i]);
        }
    }
}

__global__ __launch_bounds__(256) void k_pout(const unsigned short* __restrict__ gate,
                       const float* __restrict__ wt, const float* __restrict__ x1,
                       float* __restrict__ out, int Ns)
{
    int g = blockIdx.x*256 + threadIdx.x;      // over BB*Ns/2
    int half = Ns >> 1;
    int b = g / half, pp = (g - b*half)*2;
    int ocb = blockIdx.y * 16;
    const unsigned short* gb = gate + (size_t)b*HID*Ns + pp;
    float a0[16], a1[16];
#pragma unroll
    for (int i = 0; i < 16; ++i) { a0[i] = 0.f; a1[i] = 0.f; }
    int c = 0;
    for (; c + 8 <= HID; c += 8)
        pout_chunk<8>(gb, c, Ns, wt, ocb, a0, a1);
    pout_chunk<7>(gb, c, Ns, wt, ocb, a0, a1);   // 120..126
    const float* xb = x1 + (size_t)b*CC*Ns + pp;
    float* ob = out + (size_t)b*CC*Ns + pp;
#pragma unroll
    for (int i = 0; i < 16; ++i) {
        float2 xv = *(const float2*)(xb + (size_t)(ocb+i)*Ns);
        float2 o; o.x = xv.x + a0[i]; o.y = xv.y + a1[i];
        *(float2*)(ob + (size_t)(ocb+i)*Ns) = o;
    }
}

// ---------------- nlwt ----------------
__global__ __launch_bounds__(256) void k_nlwt(const float* __restrict__ X, float* __restrict__ A4)
{
    int g = blockIdx.x*256 + threadIdx.x;   // over BB*CC*N2
    int n = g & (N2-1); int bc = g >> 14;
    int h1 = n >> 7, w1 = n & 127;
    int hb = (h1+1)&127, wb = (w1+1)&127;
    const float* xp = X + (size_t)bc * N1;
    float t1, t2, t3, t4;
    {
        int y=h1, z=w1;
        float c0=xp[(2*y)*256+2*z], c1=xp[(2*y)*256+2*z+1], c2=xp[(2*y+1)*256+2*z], c3=xp[(2*y+1)*256+2*z+1];
        t1 = 0.5f*(-c0 - c1 - c2 + c3);
    }
    {
        int y=hb, z=w1;
        float c0=xp[(2*y)*256+2*z], c1=xp[(2*y)*256+2*z+1], c2=xp[(2*y+1)*256+2*z], c3=xp[(2*y+1)*256+2*z+1];
        t2 = 0.5f*( c0 - c1 + c2 + c3);
    }
    {
        int y=h1, z=wb;
        float c0=xp[(2*y)*256+2*z], c1=xp[(2*y)*256+2*z+1], c2=xp[(2*y+1)*256+2*z], c3=xp[(2*y+1)*256+2*z+1];
        t3 = 0.5f*( c0 + c1 - c2 + c3);
    }
    {
        int y=hb, z=wb;
        float c0=xp[(2*y)*256+2*z], c1=xp[(2*y)*256+2*z+1], c2=xp[(2*y+1)*256+2*z], c3=xp[(2*y+1)*256+2*z+1];
        t4 = 0.5f*( c0 - c1 - c2 - c3);
    }
    size_t o = (size_t)bc*N2 + n;
    A4[o]           = -t1 + t2 + t3 - t4;
    A4[PS2 + o]     = -t1 - t2 - t3 - t4;
    A4[2*PS2 + o]   = -t1 - t2 + t3 + t4;
    A4[3*PS2 + o]   =  t1 - t2 + t3 - t4;
}

// ---------------- inlwt ----------------
__global__ __launch_bounds__(256) void k_inlwt(const float* __restrict__ Ain, const float* __restrict__ A4,
                        float* __restrict__ out)
{
    int g = blockIdx.x*256 + threadIdx.x;   // over BB*CC*N2
    int n = g & (N2-1); int bc = g >> 14;
    int h1 = n >> 7, w1 = n & 127;
    int hm = (h1-1)&127, wm = (w1-1)&127;
    const float* I0 = Ain + (size_t)bc*N2;
    const float* I1 = A4 + PS2   + (size_t)bc*N2;
    const float* I2 = A4 + 2*PS2 + (size_t)bc*N2;
    const float* I3 = A4 + 3*PS2 + (size_t)bc*N2;
    int i00 = h1*128+w1, i10 = hm*128+w1, i01 = h1*128+wm, i11 = hm*128+wm;
    float t1, t2, t3, t4;
    { float a=I0[i00], b2=I1[i00], c2=I2[i00], d2=I3[i00]; t1 = -a - b2 - c2 + d2; }
    { float a=I0[i10], b2=I1[i10], c2=I2[i10], d2=I3[i10]; t2 =  a - b2 - c2 - d2; }
    { float a=I0[i01], b2=I1[i01], c2=I2[i01], d2=I3[i01]; t3 =  a - b2 + c2 + d2; }
    { float a=I0[i11], b2=I1[i11], c2=I2[i11], d2=I3[i11]; t4 = -a - b2 + c2 - d2; }
    float y00 = 0.125f*(-t1 + t2 + t3 + t4);
    float y01 = 0.125f*(-t1 - t2 + t3 - t4);
    float y10 = 0.125f*(-t1 + t2 - t3 - t4);
    float y11 = 0.125f*( t1 + t2 + t3 - t4);
    float* ob = out + (size_t)bc * N1;
    int oy = h1*2, ox = w1*2;
    ob[(size_t)oy*256 + ox]       = y00;
    ob[(size_t)oy*256 + ox + 1]   = y01;
    ob[(size_t)(oy+1)*256 + ox]   = y10;
    ob[(size_t)(oy+1)*256 + ox+1] = y11;
}

// ---------------- gfm: channel stats ----------------
__global__ __launch_bounds__(256) void k_chstat(const float* __restrict__ b1, const float* __restrict__ b2,
                         float* __restrict__ avg, float* __restrict__ mxo)
{
    int bc = blockIdx.x;            // 0..BB*96-1
    int b = bc / 96, ch = bc % 96;
    const float* src = ch < 48 ? b1 + ((size_t)b*CC + ch)*N1
                               : b2 + ((size_t)b*CC + (ch-48))*N1;
    float s = 0.f, m = -1e30f;
    for (int n = threadIdx.x; n < N1; n += 256) {
        float v = src[n]; s += v; m = fmaxf(m, v);
    }
    int lane = threadIdx.x & 63, wave = threadIdx.x >> 6;
    __shared__ float rs[4], rm[4];
#pragma unroll
    for (int off = 32; off > 0; off >>= 1) {
        s += __shfl_down(s, off);
        m = fmaxf(m, __shfl_down(m, off));
    }
    if (lane == 0) { rs[wave] = s; rm[wave] = m; }
    __syncthreads();
    if (threadIdx.x == 0) {
        float ss = rs[0]+rs[1]+rs[2]+rs[3];
        float mm = fmaxf(fmaxf(rm[0],rm[1]), fmaxf(rm[2],rm[3]));
        avg[bc] = ss * (1.0f/N1);
        mxo[bc] = mm;
    }
}

// ---------------- gfm: channel attention MLP ----------------
__global__ void k_cw(const float* __restrict__ avg, const float* __restrict__ mx,
                     const float* __restrict__ w1, const float* __restrict__ w2,
                     float* __restrict__ cw)
{
    int t = threadIdx.x;
    if (t >= BB*96) return;
    int b = t / 96, o = t % 96;
    float ta[6], tm[6];
#pragma unroll
    for (int j = 0; j < 6; ++j) {
        float sa = 0.f, sm = 0.f;
        for (int i = 0; i < 96; ++i) {
            float w = w1[j*96+i];
            sa = fmaf(w, avg[b*96+i], sa);
            sm = fmaf(w, mx[b*96+i], sm);
        }
        ta[j] = sa > 0.f ? sa : 0.f;
        tm[j] = sm > 0.f ? sm : 0.f;
    }
    float ua = 0.f, um = 0.f;
#pragma unroll
    for (int j = 0; j < 6; ++j) {
        ua = fmaf(w2[o*6+j], ta[j], ua);
        um = fmaf(w2[o*6+j], tm[j], um);
    }
    float z = ua + um;
    cw[t] = 1.0f/(1.0f+expf(-z));
}

// ---------------- gfm: weighted combine + spatial stats ----------------
__global__ __launch_bounds__(256) void k_gfm_out(const float* __restrict__ b1, const float* __restrict__ b2,
                          const float* __restrict__ cw, float* __restrict__ ob,
                          float* __restrict__ savg, float* __restrict__ smax)
{
    int g = blockIdx.x*256 + threadIdx.x;   // BB*N1
    int b = g >> 16, p = g & (N1-1);
    float s = 0.f, m = -1e30f;
#pragma unroll
    for (int c = 0; c < CC; ++c) {
        size_t idx = ((size_t)b*CC + c)*N1 + p;
        float o = cw[b*96 + c]*b1[idx] + cw[b*96 + 48 + c]*b2[idx];
        ob[idx] = o;
        s += o; m = fmaxf(m, o);
    }
    savg[(size_t)b*N1 + p] = s*(1.0f/CC);
    smax[(size_t)b*N1 + p] = m;
}

// ---------------- gfm: 7x7 spatial attention + final multiply ----------------
__global__ __launch_bounds__(256) void k_final(const float* __restrict__ savg, const float* __restrict__ smax,
                        const float* __restrict__ saw, const float* __restrict__ sab,
                        const float* __restrict__ ob, float* __restrict__ out)
{
    int g = blockIdx.x*256 + threadIdx.x;
    int b = g >> 16, p = g & (N1-1);
    int y = p >> 8, x = p & 255;
    float s = sab[0];
    const float* av = savg + (size_t)b*N1;
    const float* mx = smax + (size_t)b*N1;
#pragma unroll
    for (int ky = 0; ky < 7; ++ky) {
        int yy = y + ky - 3;
        bool yok = (yy >= 0) && (yy < 256);
        int yc = yy < 0 ? 0 : (yy > 255 ? 255 : yy);
#pragma unroll
        for (int kx = 0; kx < 7; ++kx) {
            int xx = x + kx - 3;
            bool ok = yok && (xx >= 0) && (xx < 256);
            int xc = xx < 0 ? 0 : (xx > 255 ? 255 : xx);
            int idx = yc*256 + xc;
            float a = av[idx], m2 = mx[idx];
            s = fmaf(ok ? a  : 0.f, saw[ky*7+kx], s);
            s = fmaf(ok ? m2 : 0.f, saw[49 + ky*7+kx], s);
        }
    }
    float sig = 1.0f/(1.0f+expf(-s));
#pragma unroll
    for (int c = 0; c < CC; ++c) {
        size_t idx = ((size_t)b*CC + c)*N1 + p;
        out[idx] = sig * ob[idx];
    }
}

} // anonymous namespace

extern "C" void kernel_launch(void* const* d_in, const int* in_sizes, int n_in,
                              void* d_out, int out_size, void* d_ws, size_t ws_size,
                              hipStream_t stream)
{
    const float* x    = (const float*)d_in[0];
    const float* ln1w = (const float*)d_in[1];
    const float* ln1b = (const float*)d_in[2];
    const float* temp = (const float*)d_in[3];
    const float* qkvw = (const float*)d_in[4];
    const float* qkvdw= (const float*)d_in[5];
    const float* projw= (const float*)d_in[6];
    const float* ln2w = (const float*)d_in[7];
    const float* ln2b = (const float*)d_in[8];
    const float* pinw = (const float*)d_in[9];
    const float* ffdw = (const float*)d_in[10];
    const float* poutw= (const float*)d_in[11];
    const float* caw1 = (const float*)d_in[12];
    const float* caw2 = (const float*)d_in[13];
    const float* saw  = (const float*)d_in[14];
    const float* sab  = (const float*)d_in[15];

    float* wsf  = (float*)d_ws;
    float* A4   = wsf;                               // 4 planes of (B,C,128,128)
    float* br1  = A4 + 4*PS2;
    float* br2  = br1 + NB1;
    float* x1b  = br2 + NB1;                         // tblock x1 / gfm out buffer
    float* tbA  = x1b + NB1;
    float* qkv  = tbA + PS2;                         // fp32 qkv conv out; bf16 pin_out
    float* qkvd = qkv + (size_t)BB*QKVC*N1;          // fp32 dwconv out; bf16 gate
    float* stats= qkvd + (size_t)BB*QKVC*N1;
    float* savg = stats + 4096;
    float* smax = savg + (size_t)BB*N1;
    float* wrep = smax + (size_t)BB*N1;              // repacked pout weights [127][48]

    k_repw<<<(HID*48+255)/256, 256, 0, stream>>>(poutw, wrep);

    auto tb = [&](const float* Xin, float* outp, int Hs, int Ws) {
        int Ns = Hs*Ws;
        int npix = BB*Ns;
        k_zero<<<3, 256, 0, stream>>>(stats, 768);
        dim3 g1(npix/256, QKVC/16);
        k_ln_conv<QKVC, false><<<g1, 256, 0, stream>>>(Xin, ln1w, ln1b, qkvw, qkv, Ns);
        k_dw3<<<(BB*QKVC*Ns)/256, 256, 0, stream>>>(qkv, qkvdw, qkvd, QKVC, Hs, Ws);
        k_qk_stats<<<BB*NHEAD*32, 256, 0, stream>>>(qkvd, stats, Ns);
        k_attn<<<1, 64, 0, stream>>>(stats, temp, stats + 768);
        dim3 g4(npix/256, 3);
        k_av_proj<<<g4, 256, 0, stream>>>(qkvd, stats + 768, projw, Xin, x1b, Ns);
        dim3 g5(npix/256, (PINC+15)/16);
        k_ln_conv<PINC, true><<<g5, 256, 0, stream>>>(x1b, ln2w, ln2b, pinw, qkv, Ns);
        k_dwgate<<<(BB*HID*Ns)/256, 256, 0, stream>>>((const unsigned short*)qkv, ffdw,
                                                      (unsigned short*)qkvd, Hs, Ws);
        dim3 g6(npix/512, 3);
        k_pout<<<g6, 256, 0, stream>>>((const unsigned short*)qkvd, wrep, x1b, outp, Ns);
    };

    tb(x, br1, 256, 256);
    k_nlwt<<<(BB*CC*N2)/256, 256, 0, stream>>>(x, A4);
    tb(A4, tbA, 128, 128);
    k_inlwt<<<(BB*CC*N2)/256, 256, 0, stream>>>(tbA, A4, br2);
    k_chstat<<<BB*96, 256, 0, stream>>>(br1, br2, stats + 1344, stats + 1536);
    k_cw<<<1, 256, 0, stream>>>(stats + 1344, stats + 1536, caw1, caw2, stats + 1728);
    k_gfm_out<<<(BB*N1)/256, 256, 0, stream>>>(br1, br2, stats + 1728, x1b, savg, smax);
    k_final<<<(BB*N1)/256, 256, 0, stream>>>(savg, smax, saw, sab, x1b, (float*)d_out);
}

// Round 4
// 584.866 us; speedup vs baseline: 1.7178x; 1.2342x over previous
//
#include <hip/hip_runtime.h>
#include <math.h>

namespace {

constexpr int BB   = 2;
constexpr int CC   = 48;
constexpr int NHEAD= 8;
constexpr int CPH  = 6;     // channels per head
constexpr int HID  = 127;   // int(48*2.66)
constexpr int QKVC = 144;
constexpr int PINC = 254;
constexpr int N1   = 256*256;
constexpr int N2   = 128*128;
constexpr size_t PS2 = (size_t)BB*CC*N2;   // one nlwt plane
constexpr size_t NB1 = (size_t)BB*CC*N1;

// stats layout (floats, relative to stats base):
// [0,96)    q sum-sq      (b*48 + ch)
// [96,192)  k sum-sq
// [192,768) gram          ((b*8+h)*36 + c*6+d)
// [768,1344) attn weights ((b*8+h)*36 + c*6+d)
// [1344,1536) gfm channel avg (b*96+ch)
// [1536,1728) gfm channel max
// [1728,1920) gfm cw

__device__ __forceinline__ float geluf(float x) {
    return 0.5f * x * (1.0f + erff(x * 0.70710678118654752440f));
}

__device__ __forceinline__ float b2f(unsigned short u) {
    unsigned int x = ((unsigned int)u) << 16;
    float f; __builtin_memcpy(&f, &x, 4); return f;
}
__device__ __forceinline__ unsigned short f2b(float f) {
    unsigned int x; __builtin_memcpy(&x, &f, 4);
    unsigned int r = (x + 0x7FFFu + ((x >> 16) & 1u)) >> 16;   // RNE
    return (unsigned short)r;
}
__device__ __forceinline__ unsigned int pack2(float lo, float hi) {
    return (unsigned int)f2b(lo) | ((unsigned int)f2b(hi) << 16);
}

__global__ void k_zero(float* __restrict__ p, int n)
{
    int i = blockIdx.x*256 + threadIdx.x;
    if (i < n) p[i] = 0.f;
}

// generic repack w[oc][K] -> wt[c][oc]
__global__ void k_repw(const float* __restrict__ w, float* __restrict__ wt, int O, int K)
{
    int i = blockIdx.x*256 + threadIdx.x;
    if (i < O*K) {
        int c = i / O, oc = i - c*O;
        wt[c*O + oc] = w[oc*K + c];
    }
}

// ---------------- LN (channel): fp32 in -> bf16 LN'd out, 2 px/thread ----------------
__global__ __launch_bounds__(256) void k_ln(const float* __restrict__ X,
                       const float* __restrict__ lw, const float* __restrict__ lb,
                       unsigned short* __restrict__ xh, int Ns)
{
    int g = blockIdx.x*256 + threadIdx.x;      // over BB*Ns/2
    int half = Ns >> 1;
    int b = g / half, pp = (g - b*half)*2;
    const float* xb = X + (size_t)b*CC*Ns + pp;
    float v0[CC], v1[CC];
    float s0=0.f, s20=0.f, s1=0.f, s21=0.f;
#pragma unroll
    for (int c = 0; c < CC; ++c) {
        float2 v = *(const float2*)(xb + (size_t)c*Ns);
        v0[c]=v.x; v1[c]=v.y;
        s0 += v.x; s20 = fmaf(v.x,v.x,s20);
        s1 += v.y; s21 = fmaf(v.y,v.y,s21);
    }
    float mu0 = s0*(1.0f/CC), mu1 = s1*(1.0f/CC);
    float i0 = 1.0f/sqrtf(s20*(1.0f/CC)-mu0*mu0+1e-5f);
    float i1 = 1.0f/sqrtf(s21*(1.0f/CC)-mu1*mu1+1e-5f);
    unsigned short* ob = xh + (size_t)b*CC*Ns + pp;
#pragma unroll
    for (int c = 0; c < CC; ++c) {
        float w = lw[c], bb2 = lb[c];
        float y0 = (v0[c]-mu0)*i0*w + bb2;
        float y1 = (v1[c]-mu1)*i1*w + bb2;
        *(unsigned int*)(ob + (size_t)c*Ns) = pack2(y0, y1);
    }
}

// ---------------- 1x1 conv: bf16 in (2px/thread) x repacked fp32 w -> bf16 out ----------------
template<int OC, int CH>
__device__ __forceinline__ void conv2_acc(const unsigned short* __restrict__ xb, int Ns,
                                          const float* __restrict__ wt, int ocb,
                                          unsigned short* __restrict__ ob)
{
    float a0[CH], a1[CH];
#pragma unroll
    for (int i = 0; i < CH; ++i) { a0[i]=0.f; a1[i]=0.f; }
#pragma unroll
    for (int c0 = 0; c0 < CC; c0 += 8) {
        unsigned int gv[8];
#pragma unroll
        for (int u = 0; u < 8; ++u)
            gv[u] = *(const unsigned int*)(xb + (size_t)(c0+u)*Ns);
#pragma unroll
        for (int u = 0; u < 8; ++u) {
            float t0 = b2f((unsigned short)(gv[u] & 0xffffu));
            float t1 = b2f((unsigned short)(gv[u] >> 16));
            const float* wr = wt + (c0+u)*OC + ocb;
#pragma unroll
            for (int i = 0; i < CH; ++i) {
                float w = wr[i];
                a0[i] = fmaf(t0, w, a0[i]);
                a1[i] = fmaf(t1, w, a1[i]);
            }
        }
    }
#pragma unroll
    for (int i = 0; i < CH; ++i)
        *(unsigned int*)(ob + (size_t)(ocb+i)*Ns) = pack2(a0[i], a1[i]);
}

template<int OC>
__global__ __launch_bounds__(256) void k_conv1x1(const unsigned short* __restrict__ xh,
                       const float* __restrict__ wt, unsigned short* __restrict__ out, int Ns)
{
    int g = blockIdx.x*256 + threadIdx.x;      // over BB*Ns/2
    int half = Ns >> 1;
    int b = g / half, pp = (g - b*half)*2;
    int ocb = blockIdx.y * 16;
    const unsigned short* xb = xh + (size_t)b*CC*Ns + pp;
    unsigned short* ob = out + (size_t)b*OC*Ns + pp;
    constexpr int R = (OC % 16 == 0) ? 16 : (OC % 16);
    if (ocb + 16 <= OC) conv2_acc<OC,16>(xb, Ns, wt, ocb, ob);
    else                conv2_acc<OC,R >(xb, Ns, wt, ocb, ob);
}

// ---------------- depthwise 3x3 (zero pad), bf16 in fp32 out ----------------
__device__ __forceinline__ float dw9b(const unsigned short* __restrict__ plane,
                                      const float* __restrict__ w9,
                                      int y, int x, int Hs, int Ws)
{
    float s = 0.f;
#pragma unroll
    for (int ky = 0; ky < 3; ++ky) {
        int yy = y + ky - 1;
        bool yok = (yy >= 0) && (yy < Hs);
        int yc = yy < 0 ? 0 : (yy >= Hs ? Hs-1 : yy);
#pragma unroll
        for (int kx = 0; kx < 3; ++kx) {
            int xx = x + kx - 1;
            bool ok = yok && (xx >= 0) && (xx < Ws);
            int xc = xx < 0 ? 0 : (xx >= Ws ? Ws-1 : xx);
            float v = b2f(plane[(size_t)yc*Ws + xc]);
            s = fmaf(ok ? v : 0.f, w9[ky*3+kx], s);
        }
    }
    return s;
}

__global__ __launch_bounds__(256) void k_dw3b(const unsigned short* __restrict__ in,
                      const float* __restrict__ w,
                      float* __restrict__ out, int nch, int Hs, int Ws)
{
    int Ns = Hs * Ws;
    int g = blockIdx.x * 256 + threadIdx.x;
    int p = g % Ns, bc = g / Ns;
    int c = bc % nch;
    int y = p / Ws, x = p - y * Ws;
    out[(size_t)bc * Ns + p] = dw9b(in + (size_t)bc*Ns, w + c*9, y, x, Hs, Ws);
}

// ---------------- q/k norms + gram reduction ----------------
__global__ __launch_bounds__(256) void k_qk_stats(const float* __restrict__ qkvd,
                                                  float* __restrict__ st, int Ns)
{
    const int NBLK = 32;
    int bh = blockIdx.x / NBLK, blk = blockIdx.x % NBLK;
    int b = bh / NHEAD, h = bh % NHEAD;
    const float* qb = qkvd + ((size_t)b*QKVC + h*CPH)*Ns;
    const float* kb = qkvd + ((size_t)b*QKVC + 48 + h*CPH)*Ns;
    float vals[48];
#pragma unroll
    for (int i = 0; i < 48; ++i) vals[i] = 0.f;
    for (int n = blk*256 + (int)threadIdx.x; n < Ns; n += NBLK*256) {
        float qv[CPH], kv[CPH];
#pragma unroll
        for (int i = 0; i < CPH; ++i) { qv[i] = qb[(size_t)i*Ns + n]; kv[i] = kb[(size_t)i*Ns + n]; }
#pragma unroll
        for (int i = 0; i < CPH; ++i) {
            vals[i]   = fmaf(qv[i], qv[i], vals[i]);
            vals[6+i] = fmaf(kv[i], kv[i], vals[6+i]);
        }
#pragma unroll
        for (int i = 0; i < CPH; ++i)
#pragma unroll
            for (int j = 0; j < CPH; ++j)
                vals[12 + i*6 + j] = fmaf(qv[i], kv[j], vals[12 + i*6 + j]);
    }
    __shared__ float red[4][48];
    int lane = threadIdx.x & 63, wave = threadIdx.x >> 6;
#pragma unroll
    for (int i = 0; i < 48; ++i) {
        float v = vals[i];
#pragma unroll
        for (int off = 32; off > 0; off >>= 1) v += __shfl_down(v, off);
        if (lane == 0) red[wave][i] = v;
    }
    __syncthreads();
    if ((int)threadIdx.x < 48) {
        int i = threadIdx.x;
        float v = red[0][i] + red[1][i] + red[2][i] + red[3][i];
        float* dst;
        if (i < 6)       dst = st + b*48 + h*CPH + i;
        else if (i < 12) dst = st + 96 + b*48 + h*CPH + (i-6);
        else             dst = st + 192 + (b*NHEAD+h)*36 + (i-12);
        atomicAdd(dst, v);
    }
}

// ---------------- tiny softmax over 6x6 per (b,h) ----------------
__global__ void k_attn(const float* __restrict__ st, const float* __restrict__ temp,
                       float* __restrict__ ao)
{
    int t = threadIdx.x;
    if (t >= BB*NHEAD) return;
    int b = t / NHEAD, h = t % NHEAD;
    const float* sqq = st + b*48 + h*CPH;
    const float* sqk = st + 96 + b*48 + h*CPH;
    const float* g   = st + 192 + (b*NHEAD+h)*36;
    float T = temp[h];
    float nq[CPH], nk[CPH];
#pragma unroll
    for (int i = 0; i < CPH; ++i) {
        nq[i] = fmaxf(sqrtf(sqq[i]), 1e-12f);
        nk[i] = fmaxf(sqrtf(sqk[i]), 1e-12f);
    }
    float* out = ao + (b*NHEAD+h)*36;
#pragma unroll
    for (int c = 0; c < CPH; ++c) {
        float l[CPH]; float m = -1e30f;
#pragma unroll
        for (int d = 0; d < CPH; ++d) {
            l[d] = g[c*6+d] / (nq[c]*nk[d]) * T;
            m = fmaxf(m, l[d]);
        }
        float ssum = 0.f;
#pragma unroll
        for (int d = 0; d < CPH; ++d) { l[d] = expf(l[d]-m); ssum += l[d]; }
        float r = 1.0f/ssum;
#pragma unroll
        for (int d = 0; d < CPH; ++d) out[c*6+d] = l[d]*r;
    }
}

// ---------------- attn @ v + proj 1x1 + residual (16-oc chunks) ----------------
__global__ __launch_bounds__(256) void k_av_proj(const float* __restrict__ qkvd, const float* __restrict__ attn,
                          const float* __restrict__ projw, const float* __restrict__ X,
                          float* __restrict__ x1, int Ns)
{
    int g = blockIdx.x*256 + threadIdx.x;
    int b = g / Ns, p = g - b*Ns;
    int ocb = blockIdx.y * 16;
    const float* vb = qkvd + ((size_t)b*QKVC + 96)*Ns + p;
    float vv[CC];
#pragma unroll
    for (int c = 0; c < CC; ++c) vv[c] = vb[(size_t)c*Ns];
    const float* at = attn + b*288;
    float o[CC];
#pragma unroll
    for (int h = 0; h < NHEAD; ++h)
#pragma unroll
        for (int cc = 0; cc < CPH; ++cc) {
            float acc = 0.f;
#pragma unroll
            for (int d = 0; d < CPH; ++d)
                acc = fmaf(at[(h*CPH+cc)*CPH + d], vv[h*CPH + d], acc);
            o[h*CPH+cc] = acc;
        }
    const float* xb = X + (size_t)b*CC*Ns + p;
    float* ob = x1 + (size_t)b*CC*Ns + p;
    float acc[16];
#pragma unroll
    for (int i = 0; i < 16; ++i) acc[i] = 0.f;
#pragma unroll
    for (int c = 0; c < CC; ++c) {
#pragma unroll
        for (int i = 0; i < 16; ++i)
            acc[i] = fmaf(o[c], projw[(ocb+i)*CC + c], acc[i]);
    }
#pragma unroll
    for (int i = 0; i < 16; ++i)
        ob[(size_t)(ocb+i)*Ns] = xb[(size_t)(ocb+i)*Ns] + acc[i];
}

// ---------------- ffn part 1: dw3x3 (bf16 in) + gelu gate -> bf16 ----------------
__global__ __launch_bounds__(256) void k_dwgate(const unsigned short* __restrict__ pin,
                         const float* __restrict__ dww,
                         unsigned short* __restrict__ gate, int Hs, int Ws)
{
    int Ns = Hs*Ws;
    int g = blockIdx.x*256 + threadIdx.x;     // over BB*HID*Ns
    int p = g % Ns, bc = g / Ns;
    int b = bc / HID, c = bc - b*HID;
    int y = p / Ws, x = p - y*Ws;
    const unsigned short* p1 = pin + ((size_t)b*PINC + c)*Ns;
    const unsigned short* p2 = pin + ((size_t)b*PINC + HID + c)*Ns;
    float d1 = dw9b(p1, dww + c*9,        y, x, Hs, Ws);
    float d2 = dw9b(p2, dww + (c+HID)*9,  y, x, Hs, Ws);
    gate[(size_t)bc*Ns + p] = f2b(geluf(d1) * d2);
}

// ---------------- ffn part 2: 1x1 conv 127->48 + residual ----------------
template<int U>
__device__ __forceinline__ void pout_chunk(const unsigned short* __restrict__ gb, int c0, int Ns,
                                           const float* __restrict__ wt, int ocb,
                                           float (&a0)[16], float (&a1)[16])
{
    unsigned int gv[U];
#pragma unroll
    for (int u = 0; u < U; ++u)
        gv[u] = *(const unsigned int*)(gb + (size_t)(c0+u)*Ns);
#pragma unroll
    for (int u = 0; u < U; ++u) {
        float t0 = b2f((unsigned short)(gv[u] & 0xffffu));
        float t1 = b2f((unsigned short)(gv[u] >> 16));
        const float* wr = wt + (c0+u)*48 + ocb;
#pragma unroll
        for (int i = 0; i < 16; ++i) {
            float w = wr[i];
            a0[i] = fmaf(t0, w, a0[i]);
            a1[i] = fmaf(t1, w, a1[i]);
        }
    }
}

__global__ __launch_bounds__(256) void k_pout(const unsigned short* __restrict__ gate,
                       const float* __restrict__ wt, const float* __restrict__ x1,
                       float* __restrict__ out, int Ns)
{
    int g = blockIdx.x*256 + threadIdx.x;      // over BB*Ns/2
    int half = Ns >> 1;
    int b = g / half, pp = (g - b*half)*2;
    int ocb = blockIdx.y * 16;
    const unsigned short* gb = gate + (size_t)b*HID*Ns + pp;
    float a0[16], a1[16];
#pragma unroll
    for (int i = 0; i < 16; ++i) { a0[i] = 0.f; a1[i] = 0.f; }
    int c = 0;
    for (; c + 8 <= HID; c += 8)
        pout_chunk<8>(gb, c, Ns, wt, ocb, a0, a1);
    pout_chunk<7>(gb, c, Ns, wt, ocb, a0, a1);   // 120..126
    const float* xb = x1 + (size_t)b*CC*Ns + pp;
    float* ob = out + (size_t)b*CC*Ns + pp;
#pragma unroll
    for (int i = 0; i < 16; ++i) {
        float2 xv = *(const float2*)(xb + (size_t)(ocb+i)*Ns);
        float2 o; o.x = xv.x + a0[i]; o.y = xv.y + a1[i];
        *(float2*)(ob + (size_t)(ocb+i)*Ns) = o;
    }
}

// ---------------- nlwt ----------------
__global__ __launch_bounds__(256) void k_nlwt(const float* __restrict__ X, float* __restrict__ A4)
{
    int g = blockIdx.x*256 + threadIdx.x;   // over BB*CC*N2
    int n = g & (N2-1); int bc = g >> 14;
    int h1 = n >> 7, w1 = n & 127;
    int hb = (h1+1)&127, wb = (w1+1)&127;
    const float* xp = X + (size_t)bc * N1;
    float t1, t2, t3, t4;
    {
        int y=h1, z=w1;
        float c0=xp[(2*y)*256+2*z], c1=xp[(2*y)*256+2*z+1], c2=xp[(2*y+1)*256+2*z], c3=xp[(2*y+1)*256+2*z+1];
        t1 = 0.5f*(-c0 - c1 - c2 + c3);
    }
    {
        int y=hb, z=w1;
        float c0=xp[(2*y)*256+2*z], c1=xp[(2*y)*256+2*z+1], c2=xp[(2*y+1)*256+2*z], c3=xp[(2*y+1)*256+2*z+1];
        t2 = 0.5f*( c0 - c1 + c2 + c3);
    }
    {
        int y=h1, z=wb;
        float c0=xp[(2*y)*256+2*z], c1=xp[(2*y)*256+2*z+1], c2=xp[(2*y+1)*256+2*z], c3=xp[(2*y+1)*256+2*z+1];
        t3 = 0.5f*( c0 + c1 - c2 + c3);
    }
    {
        int y=hb, z=wb;
        float c0=xp[(2*y)*256+2*z], c1=xp[(2*y)*256+2*z+1], c2=xp[(2*y+1)*256+2*z], c3=xp[(2*y+1)*256+2*z+1];
        t4 = 0.5f*( c0 - c1 - c2 - c3);
    }
    size_t o = (size_t)bc*N2 + n;
    A4[o]           = -t1 + t2 + t3 - t4;
    A4[PS2 + o]     = -t1 - t2 - t3 - t4;
    A4[2*PS2 + o]   = -t1 - t2 + t3 + t4;
    A4[3*PS2 + o]   =  t1 - t2 + t3 - t4;
}

// ---------------- inlwt ----------------
__global__ __launch_bounds__(256) void k_inlwt(const float* __restrict__ Ain, const float* __restrict__ A4,
                        float* __restrict__ out)
{
    int g = blockIdx.x*256 + threadIdx.x;   // over BB*CC*N2
    int n = g & (N2-1); int bc = g >> 14;
    int h1 = n >> 7, w1 = n & 127;
    int hm = (h1-1)&127, wm = (w1-1)&127;
    const float* I0 = Ain + (size_t)bc*N2;
    const float* I1 = A4 + PS2   + (size_t)bc*N2;
    const float* I2 = A4 + 2*PS2 + (size_t)bc*N2;
    const float* I3 = A4 + 3*PS2 + (size_t)bc*N2;
    int i00 = h1*128+w1, i10 = hm*128+w1, i01 = h1*128+wm, i11 = hm*128+wm;
    float t1, t2, t3, t4;
    { float a=I0[i00], b2=I1[i00], c2=I2[i00], d2=I3[i00]; t1 = -a - b2 - c2 + d2; }
    { float a=I0[i10], b2=I1[i10], c2=I2[i10], d2=I3[i10]; t2 =  a - b2 - c2 - d2; }
    { float a=I0[i01], b2=I1[i01], c2=I2[i01], d2=I3[i01]; t3 =  a - b2 + c2 + d2; }
    { float a=I0[i11], b2=I1[i11], c2=I2[i11], d2=I3[i11]; t4 = -a - b2 + c2 - d2; }
    float y00 = 0.125f*(-t1 + t2 + t3 + t4);
    float y01 = 0.125f*(-t1 - t2 + t3 - t4);
    float y10 = 0.125f*(-t1 + t2 - t3 - t4);
    float y11 = 0.125f*( t1 + t2 + t3 - t4);
    float* ob = out + (size_t)bc * N1;
    int oy = h1*2, ox = w1*2;
    ob[(size_t)oy*256 + ox]       = y00;
    ob[(size_t)oy*256 + ox + 1]   = y01;
    ob[(size_t)(oy+1)*256 + ox]   = y10;
    ob[(size_t)(oy+1)*256 + ox+1] = y11;
}

// ---------------- gfm: channel stats, two-stage ----------------
constexpr int CSEG = 8;
__global__ __launch_bounds__(256) void k_chstat_part(const float* __restrict__ b1, const float* __restrict__ b2,
                         float* __restrict__ ps, float* __restrict__ pm)
{
    int bc = blockIdx.x;            // 0..BB*96-1
    int seg = blockIdx.y;           // 0..CSEG-1
    int b = bc / 96, ch = bc % 96;
    const float* src = (ch < 48 ? b1 + ((size_t)b*CC + ch)*N1
                                : b2 + ((size_t)b*CC + (ch-48))*N1) + (size_t)seg*(N1/CSEG);
    const float4* s4 = (const float4*)src;
    float s = 0.f, m = -1e30f;
    for (int i = threadIdx.x; i < N1/CSEG/4; i += 256) {
        float4 v = s4[i];
        s += v.x+v.y+v.z+v.w;
        m = fmaxf(m, fmaxf(fmaxf(v.x,v.y), fmaxf(v.z,v.w)));
    }
    int lane = threadIdx.x & 63, wave = threadIdx.x >> 6;
    __shared__ float rs[4], rm[4];
#pragma unroll
    for (int off = 32; off > 0; off >>= 1) {
        s += __shfl_down(s, off);
        m = fmaxf(m, __shfl_down(m, off));
    }
    if (lane == 0) { rs[wave] = s; rm[wave] = m; }
    __syncthreads();
    if (threadIdx.x == 0) {
        ps[bc*CSEG + seg] = rs[0]+rs[1]+rs[2]+rs[3];
        pm[bc*CSEG + seg] = fmaxf(fmaxf(rm[0],rm[1]), fmaxf(rm[2],rm[3]));
    }
}

__global__ void k_chstat_fin(const float* __restrict__ ps, const float* __restrict__ pm,
                             float* __restrict__ avg, float* __restrict__ mxo)
{
    int t = threadIdx.x;
    if (t >= BB*96) return;
    float s = 0.f, m = -1e30f;
#pragma unroll
    for (int j = 0; j < CSEG; ++j) {
        s += ps[t*CSEG+j];
        m = fmaxf(m, pm[t*CSEG+j]);
    }
    avg[t] = s*(1.0f/N1);
    mxo[t] = m;
}

// ---------------- gfm: channel attention MLP ----------------
__global__ void k_cw(const float* __restrict__ avg, const float* __restrict__ mx,
                     const float* __restrict__ w1, const float* __restrict__ w2,
                     float* __restrict__ cw)
{
    int t = threadIdx.x;
    if (t >= BB*96) return;
    int b = t / 96, o = t % 96;
    float ta[6], tm[6];
#pragma unroll
    for (int j = 0; j < 6; ++j) {
        float sa = 0.f, sm = 0.f;
        for (int i = 0; i < 96; ++i) {
            float w = w1[j*96+i];
            sa = fmaf(w, avg[b*96+i], sa);
            sm = fmaf(w, mx[b*96+i], sm);
        }
        ta[j] = sa > 0.f ? sa : 0.f;
        tm[j] = sm > 0.f ? sm : 0.f;
    }
    float ua = 0.f, um = 0.f;
#pragma unroll
    for (int j = 0; j < 6; ++j) {
        ua = fmaf(w2[o*6+j], ta[j], ua);
        um = fmaf(w2[o*6+j], tm[j], um);
    }
    float z = ua + um;
    cw[t] = 1.0f/(1.0f+expf(-z));
}

// ---------------- gfm: weighted combine + spatial stats ----------------
__global__ __launch_bounds__(256) void k_gfm_out(const float* __restrict__ b1, const float* __restrict__ b2,
                          const float* __restrict__ cw, float* __restrict__ ob,
                          float* __restrict__ savg, float* __restrict__ smax)
{
    int g = blockIdx.x*256 + threadIdx.x;   // BB*N1
    int b = g >> 16, p = g & (N1-1);
    float s = 0.f, m = -1e30f;
#pragma unroll
    for (int c = 0; c < CC; ++c) {
        size_t idx = ((size_t)b*CC + c)*N1 + p;
        float o = cw[b*96 + c]*b1[idx] + cw[b*96 + 48 + c]*b2[idx];
        ob[idx] = o;
        s += o; m = fmaxf(m, o);
    }
    savg[(size_t)b*N1 + p] = s*(1.0f/CC);
    smax[(size_t)b*N1 + p] = m;
}

// ---------------- gfm: 7x7 spatial attention + final multiply ----------------
__global__ __launch_bounds__(256) void k_final(const float* __restrict__ savg, const float* __restrict__ smax,
                        const float* __restrict__ saw, const float* __restrict__ sab,
                        const float* __restrict__ ob, float* __restrict__ out)
{
    int g = blockIdx.x*256 + threadIdx.x;
    int b = g >> 16, p = g & (N1-1);
    int y = p >> 8, x = p & 255;
    float s = sab[0];
    const float* av = savg + (size_t)b*N1;
    const float* mx = smax + (size_t)b*N1;
#pragma unroll
    for (int ky = 0; ky < 7; ++ky) {
        int yy = y + ky - 3;
        bool yok = (yy >= 0) && (yy < 256);
        int yc = yy < 0 ? 0 : (yy > 255 ? 255 : yy);
#pragma unroll
        for (int kx = 0; kx < 7; ++kx) {
            int xx = x + kx - 3;
            bool ok = yok && (xx >= 0) && (xx < 256);
            int xc = xx < 0 ? 0 : (xx > 255 ? 255 : xx);
            int idx = yc*256 + xc;
            float a = av[idx], m2 = mx[idx];
            s = fmaf(ok ? a  : 0.f, saw[ky*7+kx], s);
            s = fmaf(ok ? m2 : 0.f, saw[49 + ky*7+kx], s);
        }
    }
    float sig = 1.0f/(1.0f+expf(-s));
#pragma unroll
    for (int c = 0; c < CC; ++c) {
        size_t idx = ((size_t)b*CC + c)*N1 + p;
        out[idx] = sig * ob[idx];
    }
}

} // anonymous namespace

extern "C" void kernel_launch(void* const* d_in, const int* in_sizes, int n_in,
                              void* d_out, int out_size, void* d_ws, size_t ws_size,
                              hipStream_t stream)
{
    const float* x    = (const float*)d_in[0];
    const float* ln1w = (const float*)d_in[1];
    const float* ln1b = (const float*)d_in[2];
    const float* temp = (const float*)d_in[3];
    const float* qkvw = (const float*)d_in[4];
    const float* qkvdw= (const float*)d_in[5];
    const float* projw= (const float*)d_in[6];
    const float* ln2w = (const float*)d_in[7];
    const float* ln2b = (const float*)d_in[8];
    const float* pinw = (const float*)d_in[9];
    const float* ffdw = (const float*)d_in[10];
    const float* poutw= (const float*)d_in[11];
    const float* caw1 = (const float*)d_in[12];
    const float* caw2 = (const float*)d_in[13];
    const float* saw  = (const float*)d_in[14];
    const float* sab  = (const float*)d_in[15];

    float* wsf  = (float*)d_ws;
    float* A4   = wsf;                               // 4 planes of (B,C,128,128)
    float* br1  = A4 + 4*PS2;
    float* br2  = br1 + NB1;
    float* x1b  = br2 + NB1;                         // tblock x1 / gfm out buffer
    float* tbA  = x1b + NB1;
    float* qkv  = tbA + PS2;                         // bf16 qkv conv out / bf16 pin_out
    float* qkvd = qkv + (size_t)BB*QKVC*N1;          // bf16 xhat; fp32 dwconv out; bf16 gate
    float* stats= qkvd + (size_t)BB*QKVC*N1;
    float* wqr  = stats + 4096;                      // repacked qkv w [48][144]
    float* wpr  = wqr + 48*QKVC;                     // repacked pin w [48][254]
    float* wor  = wpr + 48*PINC;                     // repacked pout w [127][48]
    float* chps = wor + HID*48;                      // chstat partial sums [192*8]
    float* chpm = chps + 192*CSEG;                   // chstat partial maxs
    float* savg = chpm + 192*CSEG;
    float* smax = savg + (size_t)BB*N1;

    k_repw<<<(48*QKVC+255)/256, 256, 0, stream>>>(qkvw, wqr, QKVC, 48);
    k_repw<<<(48*PINC+255)/256, 256, 0, stream>>>(pinw, wpr, PINC, 48);
    k_repw<<<(HID*48+255)/256, 256, 0, stream>>>(poutw, wor, 48, HID);

    auto tb = [&](const float* Xin, float* outp, int Hs, int Ws) {
        int Ns = Hs*Ws;
        int npix = BB*Ns;
        unsigned short* xhat = (unsigned short*)qkvd;   // dead before dw3b/dwgate write qkvd
        k_zero<<<3, 256, 0, stream>>>(stats, 768);
        k_ln<<<npix/512, 256, 0, stream>>>(Xin, ln1w, ln1b, xhat, Ns);
        dim3 gq(npix/512, QKVC/16);
        k_conv1x1<QKVC><<<gq, 256, 0, stream>>>(xhat, wqr, (unsigned short*)qkv, Ns);
        k_dw3b<<<(BB*QKVC*Ns)/256, 256, 0, stream>>>((const unsigned short*)qkv, qkvdw, qkvd, QKVC, Hs, Ws);
        k_qk_stats<<<BB*NHEAD*32, 256, 0, stream>>>(qkvd, stats, Ns);
        k_attn<<<1, 64, 0, stream>>>(stats, temp, stats + 768);
        dim3 g4(npix/256, 3);
        k_av_proj<<<g4, 256, 0, stream>>>(qkvd, stats + 768, projw, Xin, x1b, Ns);
        k_ln<<<npix/512, 256, 0, stream>>>(x1b, ln2w, ln2b, xhat, Ns);
        dim3 gp(npix/512, (PINC+15)/16);
        k_conv1x1<PINC><<<gp, 256, 0, stream>>>(xhat, wpr, (unsigned short*)qkv, Ns);
        k_dwgate<<<(BB*HID*Ns)/256, 256, 0, stream>>>((const unsigned short*)qkv, ffdw,
                                                      (unsigned short*)qkvd, Hs, Ws);
        dim3 g6(npix/512, 3);
        k_pout<<<g6, 256, 0, stream>>>((const unsigned short*)qkvd, wor, x1b, outp, Ns);
    };

    tb(x, br1, 256, 256);
    k_nlwt<<<(BB*CC*N2)/256, 256, 0, stream>>>(x, A4);
    tb(A4, tbA, 128, 128);
    k_inlwt<<<(BB*CC*N2)/256, 256, 0, stream>>>(tbA, A4, br2);
    dim3 gc(BB*96, CSEG);
    k_chstat_part<<<gc, 256, 0, stream>>>(br1, br2, chps, chpm);
    k_chstat_fin<<<1, 256, 0, stream>>>(chps, chpm, stats + 1344, stats + 1536);
    k_cw<<<1, 256, 0, stream>>>(stats + 1344, stats + 1536, caw1, caw2, stats + 1728);
    k_gfm_out<<<(BB*N1)/256, 256, 0, stream>>>(br1, br2, stats + 1728, x1b, savg, smax);
    k_final<<<(BB*N1)/256, 256, 0, stream>>>(savg, smax, saw, sab, x1b, (float*)d_out);
}

// Round 5
// 498.281 us; speedup vs baseline: 2.0163x; 1.1738x over previous
//
#include <hip/hip_runtime.h>
#include <math.h>

namespace {

constexpr int BB   = 2;
constexpr int CC   = 48;
constexpr int NHEAD= 8;
constexpr int CPH  = 6;     // channels per head
constexpr int HID  = 127;   // int(48*2.66)
constexpr int QKVC = 144;
constexpr int PINC = 254;
constexpr int N1   = 256*256;
constexpr int N2   = 128*128;
constexpr size_t PS2 = (size_t)BB*CC*N2;   // one nlwt plane
constexpr size_t NB1 = (size_t)BB*CC*N1;

__device__ __forceinline__ float b2f(unsigned short u) {
    unsigned int x = ((unsigned int)u) << 16;
    float f; __builtin_memcpy(&f, &x, 4); return f;
}
__device__ __forceinline__ unsigned short f2b(float f) {
    unsigned int x; __builtin_memcpy(&x, &f, 4);
    unsigned int r = (x + 0x7FFFu + ((x >> 16) & 1u)) >> 16;   // RNE
    return (unsigned short)r;
}
__device__ __forceinline__ unsigned int pack2(float lo, float hi) {
    return (unsigned int)f2b(lo) | ((unsigned int)f2b(hi) << 16);
}

// tanh-form GELU via hw exp (|err vs erf-GELU| < ~1e-3, within bf16 tolerance)
__device__ __forceinline__ float gelu_t(float x) {
    float z = 1.5957691216057308f * (x + 0.044715f * x * x * x);  // 2*sqrt(2/pi)*(...)
    float e = __expf(z);
    return x * (1.0f - 1.0f / (e + 1.0f));   // 0.5x(1+tanh(z/2)) = x*sigmoid(z)
}

__global__ void k_zero(float* __restrict__ p, int n)
{
    int i = blockIdx.x*256 + threadIdx.x;
    if (i < n) p[i] = 0.f;
}

// generic repack w[oc][K] -> wt[c][oc]
__global__ void k_repw(const float* __restrict__ w, float* __restrict__ wt, int O, int K)
{
    int i = blockIdx.x*256 + threadIdx.x;
    if (i < O*K) {
        int c = i / O, oc = i - c*O;
        wt[c*O + oc] = w[oc*K + c];
    }
}

// ---------------- LN (channel): fp32 in -> bf16 LN'd out, 2 px/thread ----------------
__global__ __launch_bounds__(256) void k_ln(const float* __restrict__ X,
                       const float* __restrict__ lw, const float* __restrict__ lb,
                       unsigned short* __restrict__ xh, int Ns)
{
    int g = blockIdx.x*256 + threadIdx.x;      // over BB*Ns/2
    int half = Ns >> 1;
    int b = g / half, pp = (g - b*half)*2;
    const float* xb = X + (size_t)b*CC*Ns + pp;
    float v0[CC], v1[CC];
    float s0=0.f, s20=0.f, s1=0.f, s21=0.f;
#pragma unroll
    for (int c = 0; c < CC; ++c) {
        float2 v = *(const float2*)(xb + (size_t)c*Ns);
        v0[c]=v.x; v1[c]=v.y;
        s0 += v.x; s20 = fmaf(v.x,v.x,s20);
        s1 += v.y; s21 = fmaf(v.y,v.y,s21);
    }
    float mu0 = s0*(1.0f/CC), mu1 = s1*(1.0f/CC);
    float i0 = 1.0f/sqrtf(s20*(1.0f/CC)-mu0*mu0+1e-5f);
    float i1 = 1.0f/sqrtf(s21*(1.0f/CC)-mu1*mu1+1e-5f);
    unsigned short* ob = xh + (size_t)b*CC*Ns + pp;
#pragma unroll
    for (int c = 0; c < CC; ++c) {
        float w = lw[c], bb2 = lb[c];
        float y0 = (v0[c]-mu0)*i0*w + bb2;
        float y1 = (v1[c]-mu1)*i1*w + bb2;
        *(unsigned int*)(ob + (size_t)c*Ns) = pack2(y0, y1);
    }
}

// ---------------- 1x1 conv: bf16 in (2px/thread) x repacked fp32 w -> bf16 out ----------------
template<int OC, int CH>
__device__ __forceinline__ void conv2_acc(const unsigned short* __restrict__ xb, int Ns,
                                          const float* __restrict__ wt, int ocb,
                                          unsigned short* __restrict__ ob)
{
    float a0[CH], a1[CH];
#pragma unroll
    for (int i = 0; i < CH; ++i) { a0[i]=0.f; a1[i]=0.f; }
#pragma unroll
    for (int c0 = 0; c0 < CC; c0 += 8) {
        unsigned int gv[8];
#pragma unroll
        for (int u = 0; u < 8; ++u)
            gv[u] = *(const unsigned int*)(xb + (size_t)(c0+u)*Ns);
#pragma unroll
        for (int u = 0; u < 8; ++u) {
            float t0 = b2f((unsigned short)(gv[u] & 0xffffu));
            float t1 = b2f((unsigned short)(gv[u] >> 16));
            const float* wr = wt + (c0+u)*OC + ocb;
#pragma unroll
            for (int i = 0; i < CH; ++i) {
                float w = wr[i];
                a0[i] = fmaf(t0, w, a0[i]);
                a1[i] = fmaf(t1, w, a1[i]);
            }
        }
    }
#pragma unroll
    for (int i = 0; i < CH; ++i)
        *(unsigned int*)(ob + (size_t)(ocb+i)*Ns) = pack2(a0[i], a1[i]);
}

template<int OC>
__global__ __launch_bounds__(256) void k_conv1x1(const unsigned short* __restrict__ xh,
                       const float* __restrict__ wt, unsigned short* __restrict__ out, int Ns)
{
    int g = blockIdx.x*256 + threadIdx.x;      // over BB*Ns/2
    int half = Ns >> 1;
    int b = g / half, pp = (g - b*half)*2;
    int ocb = blockIdx.y * 16;
    const unsigned short* xb = xh + (size_t)b*CC*Ns + pp;
    unsigned short* ob = out + (size_t)b*OC*Ns + pp;
    constexpr int R = (OC % 16 == 0) ? 16 : (OC % 16);
    if (ocb + 16 <= OC) conv2_acc<OC,16>(xb, Ns, wt, ocb, ob);
    else                conv2_acc<OC,R >(xb, Ns, wt, ocb, ob);
}

// ---------------- row-vectorized depthwise 3x3 (zero pad), 8 px/thread ----------------
__device__ __forceinline__ void load_row10(const unsigned short* __restrict__ p,
                                           bool rok, bool lok, bool rrok, float (&f)[10])
{
    if (rok) {
        uint4 cv = *(const uint4*)p;            // 8 bf16, 16B aligned
        unsigned int u0=cv.x,u1=cv.y,u2=cv.z,u3=cv.w;
        f[1]=b2f((unsigned short)(u0&0xffffu)); f[2]=b2f((unsigned short)(u0>>16));
        f[3]=b2f((unsigned short)(u1&0xffffu)); f[4]=b2f((unsigned short)(u1>>16));
        f[5]=b2f((unsigned short)(u2&0xffffu)); f[6]=b2f((unsigned short)(u2>>16));
        f[7]=b2f((unsigned short)(u3&0xffffu)); f[8]=b2f((unsigned short)(u3>>16));
        f[0] = lok  ? b2f(p[-1]) : 0.f;
        f[9] = rrok ? b2f(p[8])  : 0.f;
    } else {
#pragma unroll
        for (int i = 0; i < 10; ++i) f[i] = 0.f;
    }
}

__device__ __forceinline__ void dw8(const unsigned short* __restrict__ plane,
                                    const float* __restrict__ w9,
                                    int y, int x0, int Hs, int Ws, float (&o)[8])
{
#pragma unroll
    for (int i = 0; i < 8; ++i) o[i] = 0.f;
#pragma unroll
    for (int dy = 0; dy < 3; ++dy) {
        int r = y + dy - 1;
        bool rok = (r >= 0) && (r < Hs);
        float f[10];
        const unsigned short* p = plane + (size_t)(rok ? r : 0)*Ws + x0;
        load_row10(p, rok, x0 > 0, x0 + 8 < Ws, f);
        float w0 = w9[dy*3], w1 = w9[dy*3+1], w2 = w9[dy*3+2];
#pragma unroll
        for (int i = 0; i < 8; ++i)
            o[i] = fmaf(f[i], w0, fmaf(f[i+1], w1, fmaf(f[i+2], w2, o[i])));
    }
}

// qkv path: bf16 in -> fp32 out
__global__ __launch_bounds__(256) void k_dw3v(const unsigned short* __restrict__ in,
                      const float* __restrict__ w,
                      float* __restrict__ out, int nch, int Hs, int Ws)
{
    int Ns = Hs * Ws, ng = Ns >> 3, wq = Ws >> 3;
    int g = blockIdx.x*256 + threadIdx.x;    // over BB*nch*ng
    int t = g % ng, bc = g / ng;
    int c = bc % nch;
    int y = t / wq, x0 = (t - y*wq) << 3;
    float o[8];
    dw8(in + (size_t)bc*Ns, w + c*9, y, x0, Hs, Ws, o);
    float4* ob = (float4*)(out + (size_t)bc*Ns + y*Ws + x0);
    ob[0] = make_float4(o[0],o[1],o[2],o[3]);
    ob[1] = make_float4(o[4],o[5],o[6],o[7]);
}

// ffn path: two planes + gelu gate -> bf16
__global__ __launch_bounds__(256) void k_dwgate(const unsigned short* __restrict__ pin,
                         const float* __restrict__ dww,
                         unsigned short* __restrict__ gate, int Hs, int Ws)
{
    int Ns = Hs * Ws, ng = Ns >> 3, wq = Ws >> 3;
    int g = blockIdx.x*256 + threadIdx.x;    // over BB*HID*ng
    int t = g % ng, bc = g / ng;
    int b = bc / HID, c = bc - b*HID;
    int y = t / wq, x0 = (t - y*wq) << 3;
    float d1[8], d2[8];
    dw8(pin + ((size_t)b*PINC + c)*Ns,       dww + c*9,         y, x0, Hs, Ws, d1);
    dw8(pin + ((size_t)b*PINC + HID + c)*Ns, dww + (c+HID)*9,   y, x0, Hs, Ws, d2);
    uint4 r;
    r.x = pack2(gelu_t(d1[0])*d2[0], gelu_t(d1[1])*d2[1]);
    r.y = pack2(gelu_t(d1[2])*d2[2], gelu_t(d1[3])*d2[3]);
    r.z = pack2(gelu_t(d1[4])*d2[4], gelu_t(d1[5])*d2[5]);
    r.w = pack2(gelu_t(d1[6])*d2[6], gelu_t(d1[7])*d2[7]);
    *(uint4*)(gate + (size_t)bc*Ns + y*Ws + x0) = r;
}

// ---------------- q/k norms + gram reduction ----------------
__global__ __launch_bounds__(256) void k_qk_stats(const float* __restrict__ qkvd,
                                                  float* __restrict__ st, int Ns)
{
    const int NBLK = 32;
    int bh = blockIdx.x / NBLK, blk = blockIdx.x % NBLK;
    int b = bh / NHEAD, h = bh % NHEAD;
    const float* qb = qkvd + ((size_t)b*QKVC + h*CPH)*Ns;
    const float* kb = qkvd + ((size_t)b*QKVC + 48 + h*CPH)*Ns;
    float vals[48];
#pragma unroll
    for (int i = 0; i < 48; ++i) vals[i] = 0.f;
    for (int n = blk*256 + (int)threadIdx.x; n < Ns; n += NBLK*256) {
        float qv[CPH], kv[CPH];
#pragma unroll
        for (int i = 0; i < CPH; ++i) { qv[i] = qb[(size_t)i*Ns + n]; kv[i] = kb[(size_t)i*Ns + n]; }
#pragma unroll
        for (int i = 0; i < CPH; ++i) {
            vals[i]   = fmaf(qv[i], qv[i], vals[i]);
            vals[6+i] = fmaf(kv[i], kv[i], vals[6+i]);
        }
#pragma unroll
        for (int i = 0; i < CPH; ++i)
#pragma unroll
            for (int j = 0; j < CPH; ++j)
                vals[12 + i*6 + j] = fmaf(qv[i], kv[j], vals[12 + i*6 + j]);
    }
    __shared__ float red[4][48];
    int lane = threadIdx.x & 63, wave = threadIdx.x >> 6;
#pragma unroll
    for (int i = 0; i < 48; ++i) {
        float v = vals[i];
#pragma unroll
        for (int off = 32; off > 0; off >>= 1) v += __shfl_down(v, off);
        if (lane == 0) red[wave][i] = v;
    }
    __syncthreads();
    if ((int)threadIdx.x < 48) {
        int i = threadIdx.x;
        float v = red[0][i] + red[1][i] + red[2][i] + red[3][i];
        float* dst;
        if (i < 6)       dst = st + b*48 + h*CPH + i;
        else if (i < 12) dst = st + 96 + b*48 + h*CPH + (i-6);
        else             dst = st + 192 + (b*NHEAD+h)*36 + (i-12);
        atomicAdd(dst, v);
    }
}

// ---------------- tiny softmax over 6x6 per (b,h) ----------------
__global__ void k_attn(const float* __restrict__ st, const float* __restrict__ temp,
                       float* __restrict__ ao)
{
    int t = threadIdx.x;
    if (t >= BB*NHEAD) return;
    int b = t / NHEAD, h = t % NHEAD;
    const float* sqq = st + b*48 + h*CPH;
    const float* sqk = st + 96 + b*48 + h*CPH;
    const float* g   = st + 192 + (b*NHEAD+h)*36;
    float T = temp[h];
    float nq[CPH], nk[CPH];
#pragma unroll
    for (int i = 0; i < CPH; ++i) {
        nq[i] = fmaxf(sqrtf(sqq[i]), 1e-12f);
        nk[i] = fmaxf(sqrtf(sqk[i]), 1e-12f);
    }
    float* out = ao + (b*NHEAD+h)*36;
#pragma unroll
    for (int c = 0; c < CPH; ++c) {
        float l[CPH]; float m = -1e30f;
#pragma unroll
        for (int d = 0; d < CPH; ++d) {
            l[d] = g[c*6+d] / (nq[c]*nk[d]) * T;
            m = fmaxf(m, l[d]);
        }
        float ssum = 0.f;
#pragma unroll
        for (int d = 0; d < CPH; ++d) { l[d] = expf(l[d]-m); ssum += l[d]; }
        float r = 1.0f/ssum;
#pragma unroll
        for (int d = 0; d < CPH; ++d) out[c*6+d] = l[d]*r;
    }
}

// ---------------- attn @ v + proj 1x1 + residual (16-oc chunks) ----------------
__global__ __launch_bounds__(256) void k_av_proj(const float* __restrict__ qkvd, const float* __restrict__ attn,
                          const float* __restrict__ projw, const float* __restrict__ X,
                          float* __restrict__ x1, int Ns)
{
    int g = blockIdx.x*256 + threadIdx.x;
    int b = g / Ns, p = g - b*Ns;
    int ocb = blockIdx.y * 16;
    const float* vb = qkvd + ((size_t)b*QKVC + 96)*Ns + p;
    float vv[CC];
#pragma unroll
    for (int c = 0; c < CC; ++c) vv[c] = vb[(size_t)c*Ns];
    const float* at = attn + b*288;
    float o[CC];
#pragma unroll
    for (int h = 0; h < NHEAD; ++h)
#pragma unroll
        for (int cc = 0; cc < CPH; ++cc) {
            float acc = 0.f;
#pragma unroll
            for (int d = 0; d < CPH; ++d)
                acc = fmaf(at[(h*CPH+cc)*CPH + d], vv[h*CPH + d], acc);
            o[h*CPH+cc] = acc;
        }
    const float* xb = X + (size_t)b*CC*Ns + p;
    float* ob = x1 + (size_t)b*CC*Ns + p;
    float acc[16];
#pragma unroll
    for (int i = 0; i < 16; ++i) acc[i] = 0.f;
#pragma unroll
    for (int c = 0; c < CC; ++c) {
#pragma unroll
        for (int i = 0; i < 16; ++i)
            acc[i] = fmaf(o[c], projw[(ocb+i)*CC + c], acc[i]);
    }
#pragma unroll
    for (int i = 0; i < 16; ++i)
        ob[(size_t)(ocb+i)*Ns] = xb[(size_t)(ocb+i)*Ns] + acc[i];
}

// ---------------- ffn part 2: 1x1 conv 127->48 + residual ----------------
template<int U>
__device__ __forceinline__ void pout_chunk(const unsigned short* __restrict__ gb, int c0, int Ns,
                                           const float* __restrict__ wt, int ocb,
                                           float (&a0)[16], float (&a1)[16])
{
    unsigned int gv[U];
#pragma unroll
    for (int u = 0; u < U; ++u)
        gv[u] = *(const unsigned int*)(gb + (size_t)(c0+u)*Ns);
#pragma unroll
    for (int u = 0; u < U; ++u) {
        float t0 = b2f((unsigned short)(gv[u] & 0xffffu));
        float t1 = b2f((unsigned short)(gv[u] >> 16));
        const float* wr = wt + (c0+u)*48 + ocb;
#pragma unroll
        for (int i = 0; i < 16; ++i) {
            float w = wr[i];
            a0[i] = fmaf(t0, w, a0[i]);
            a1[i] = fmaf(t1, w, a1[i]);
        }
    }
}

__global__ __launch_bounds__(256) void k_pout(const unsigned short* __restrict__ gate,
                       const float* __restrict__ wt, const float* __restrict__ x1,
                       float* __restrict__ out, int Ns)
{
    int g = blockIdx.x*256 + threadIdx.x;      // over BB*Ns/2
    int half = Ns >> 1;
    int b = g / half, pp = (g - b*half)*2;
    int ocb = blockIdx.y * 16;
    const unsigned short* gb = gate + (size_t)b*HID*Ns + pp;
    float a0[16], a1[16];
#pragma unroll
    for (int i = 0; i < 16; ++i) { a0[i] = 0.f; a1[i] = 0.f; }
    int c = 0;
    for (; c + 8 <= HID; c += 8)
        pout_chunk<8>(gb, c, Ns, wt, ocb, a0, a1);
    pout_chunk<7>(gb, c, Ns, wt, ocb, a0, a1);   // 120..126
    const float* xb = x1 + (size_t)b*CC*Ns + pp;
    float* ob = out + (size_t)b*CC*Ns + pp;
#pragma unroll
    for (int i = 0; i < 16; ++i) {
        float2 xv = *(const float2*)(xb + (size_t)(ocb+i)*Ns);
        float2 o; o.x = xv.x + a0[i]; o.y = xv.y + a1[i];
        *(float2*)(ob + (size_t)(ocb+i)*Ns) = o;
    }
}

// ---------------- nlwt ----------------
__global__ __launch_bounds__(256) void k_nlwt(const float* __restrict__ X, float* __restrict__ A4)
{
    int g = blockIdx.x*256 + threadIdx.x;   // over BB*CC*N2
    int n = g & (N2-1); int bc = g >> 14;
    int h1 = n >> 7, w1 = n & 127;
    int hb = (h1+1)&127, wb = (w1+1)&127;
    const float* xp = X + (size_t)bc * N1;
    float t1, t2, t3, t4;
    {
        int y=h1, z=w1;
        float c0=xp[(2*y)*256+2*z], c1=xp[(2*y)*256+2*z+1], c2=xp[(2*y+1)*256+2*z], c3=xp[(2*y+1)*256+2*z+1];
        t1 = 0.5f*(-c0 - c1 - c2 + c3);
    }
    {
        int y=hb, z=w1;
        float c0=xp[(2*y)*256+2*z], c1=xp[(2*y)*256+2*z+1], c2=xp[(2*y+1)*256+2*z], c3=xp[(2*y+1)*256+2*z+1];
        t2 = 0.5f*( c0 - c1 + c2 + c3);
    }
    {
        int y=h1, z=wb;
        float c0=xp[(2*y)*256+2*z], c1=xp[(2*y)*256+2*z+1], c2=xp[(2*y+1)*256+2*z], c3=xp[(2*y+1)*256+2*z+1];
        t3 = 0.5f*( c0 + c1 - c2 + c3);
    }
    {
        int y=hb, z=wb;
        float c0=xp[(2*y)*256+2*z], c1=xp[(2*y)*256+2*z+1], c2=xp[(2*y+1)*256+2*z], c3=xp[(2*y+1)*256+2*z+1];
        t4 = 0.5f*( c0 - c1 - c2 - c3);
    }
    size_t o = (size_t)bc*N2 + n;
    A4[o]           = -t1 + t2 + t3 - t4;
    A4[PS2 + o]     = -t1 - t2 - t3 - t4;
    A4[2*PS2 + o]   = -t1 - t2 + t3 + t4;
    A4[3*PS2 + o]   =  t1 - t2 + t3 - t4;
}

// ---------------- inlwt ----------------
__global__ __launch_bounds__(256) void k_inlwt(const float* __restrict__ Ain, const float* __restrict__ A4,
                        float* __restrict__ out)
{
    int g = blockIdx.x*256 + threadIdx.x;   // over BB*CC*N2
    int n = g & (N2-1); int bc = g >> 14;
    int h1 = n >> 7, w1 = n & 127;
    int hm = (h1-1)&127, wm = (w1-1)&127;
    const float* I0 = Ain + (size_t)bc*N2;
    const float* I1 = A4 + PS2   + (size_t)bc*N2;
    const float* I2 = A4 + 2*PS2 + (size_t)bc*N2;
    const float* I3 = A4 + 3*PS2 + (size_t)bc*N2;
    int i00 = h1*128+w1, i10 = hm*128+w1, i01 = h1*128+wm, i11 = hm*128+wm;
    float t1, t2, t3, t4;
    { float a=I0[i00], b2=I1[i00], c2=I2[i00], d2=I3[i00]; t1 = -a - b2 - c2 + d2; }
    { float a=I0[i10], b2=I1[i10], c2=I2[i10], d2=I3[i10]; t2 =  a - b2 - c2 - d2; }
    { float a=I0[i01], b2=I1[i01], c2=I2[i01], d2=I3[i01]; t3 =  a - b2 + c2 + d2; }
    { float a=I0[i11], b2=I1[i11], c2=I2[i11], d2=I3[i11]; t4 = -a - b2 + c2 - d2; }
    float y00 = 0.125f*(-t1 + t2 + t3 + t4);
    float y01 = 0.125f*(-t1 - t2 + t3 - t4);
    float y10 = 0.125f*(-t1 + t2 - t3 - t4);
    float y11 = 0.125f*( t1 + t2 + t3 - t4);
    float* ob = out + (size_t)bc * N1;
    int oy = h1*2, ox = w1*2;
    ob[(size_t)oy*256 + ox]       = y00;
    ob[(size_t)oy*256 + ox + 1]   = y01;
    ob[(size_t)(oy+1)*256 + ox]   = y10;
    ob[(size_t)(oy+1)*256 + ox+1] = y11;
}

// ---------------- gfm: channel stats, two-stage ----------------
constexpr int CSEG = 8;
__global__ __launch_bounds__(256) void k_chstat_part(const float* __restrict__ b1, const float* __restrict__ b2,
                         float* __restrict__ ps, float* __restrict__ pm)
{
    int bc = blockIdx.x;            // 0..BB*96-1
    int seg = blockIdx.y;           // 0..CSEG-1
    int b = bc / 96, ch = bc % 96;
    const float* src = (ch < 48 ? b1 + ((size_t)b*CC + ch)*N1
                                : b2 + ((size_t)b*CC + (ch-48))*N1) + (size_t)seg*(N1/CSEG);
    const float4* s4 = (const float4*)src;
    float s = 0.f, m = -1e30f;
    for (int i = threadIdx.x; i < N1/CSEG/4; i += 256) {
        float4 v = s4[i];
        s += v.x+v.y+v.z+v.w;
        m = fmaxf(m, fmaxf(fmaxf(v.x,v.y), fmaxf(v.z,v.w)));
    }
    int lane = threadIdx.x & 63, wave = threadIdx.x >> 6;
    __shared__ float rs[4], rm[4];
#pragma unroll
    for (int off = 32; off > 0; off >>= 1) {
        s += __shfl_down(s, off);
        m = fmaxf(m, __shfl_down(m, off));
    }
    if (lane == 0) { rs[wave] = s; rm[wave] = m; }
    __syncthreads();
    if (threadIdx.x == 0) {
        ps[bc*CSEG + seg] = rs[0]+rs[1]+rs[2]+rs[3];
        pm[bc*CSEG + seg] = fmaxf(fmaxf(rm[0],rm[1]), fmaxf(rm[2],rm[3]));
    }
}

__global__ void k_chstat_fin(const float* __restrict__ ps, const float* __restrict__ pm,
                             float* __restrict__ avg, float* __restrict__ mxo)
{
    int t = threadIdx.x;
    if (t >= BB*96) return;
    float s = 0.f, m = -1e30f;
#pragma unroll
    for (int j = 0; j < CSEG; ++j) {
        s += ps[t*CSEG+j];
        m = fmaxf(m, pm[t*CSEG+j]);
    }
    avg[t] = s*(1.0f/N1);
    mxo[t] = m;
}

// ---------------- gfm: channel attention MLP ----------------
__global__ void k_cw(const float* __restrict__ avg, const float* __restrict__ mx,
                     const float* __restrict__ w1, const float* __restrict__ w2,
                     float* __restrict__ cw)
{
    int t = threadIdx.x;
    if (t >= BB*96) return;
    int b = t / 96, o = t % 96;
    float ta[6], tm[6];
#pragma unroll
    for (int j = 0; j < 6; ++j) {
        float sa = 0.f, sm = 0.f;
        for (int i = 0; i < 96; ++i) {
            float w = w1[j*96+i];
            sa = fmaf(w, avg[b*96+i], sa);
            sm = fmaf(w, mx[b*96+i], sm);
        }
        ta[j] = sa > 0.f ? sa : 0.f;
        tm[j] = sm > 0.f ? sm : 0.f;
    }
    float ua = 0.f, um = 0.f;
#pragma unroll
    for (int j = 0; j < 6; ++j) {
        ua = fmaf(w2[o*6+j], ta[j], ua);
        um = fmaf(w2[o*6+j], tm[j], um);
    }
    float z = ua + um;
    cw[t] = 1.0f/(1.0f+expf(-z));
}

// ---------------- gfm: weighted combine + spatial stats ----------------
__global__ __launch_bounds__(256) void k_gfm_out(const float* __restrict__ b1, const float* __restrict__ b2,
                          const float* __restrict__ cw, float* __restrict__ ob,
                          float* __restrict__ savg, float* __restrict__ smax)
{
    int g = blockIdx.x*256 + threadIdx.x;   // BB*N1
    int b = g >> 16, p = g & (N1-1);
    float s = 0.f, m = -1e30f;
#pragma unroll
    for (int c = 0; c < CC; ++c) {
        size_t idx = ((size_t)b*CC + c)*N1 + p;
        float o = cw[b*96 + c]*b1[idx] + cw[b*96 + 48 + c]*b2[idx];
        ob[idx] = o;
        s += o; m = fmaxf(m, o);
    }
    savg[(size_t)b*N1 + p] = s*(1.0f/CC);
    smax[(size_t)b*N1 + p] = m;
}

// ---------------- gfm: 7x7 spatial attention + final multiply ----------------
__global__ __launch_bounds__(256) void k_final(const float* __restrict__ savg, const float* __restrict__ smax,
                        const float* __restrict__ saw, const float* __restrict__ sab,
                        const float* __restrict__ ob, float* __restrict__ out)
{
    int g = blockIdx.x*256 + threadIdx.x;
    int b = g >> 16, p = g & (N1-1);
    int y = p >> 8, x = p & 255;
    float s = sab[0];
    const float* av = savg + (size_t)b*N1;
    const float* mx = smax + (size_t)b*N1;
#pragma unroll
    for (int ky = 0; ky < 7; ++ky) {
        int yy = y + ky - 3;
        bool yok = (yy >= 0) && (yy < 256);
        int yc = yy < 0 ? 0 : (yy > 255 ? 255 : yy);
#pragma unroll
        for (int kx = 0; kx < 7; ++kx) {
            int xx = x + kx - 3;
            bool ok = yok && (xx >= 0) && (xx < 256);
            int xc = xx < 0 ? 0 : (xx > 255 ? 255 : xx);
            int idx = yc*256 + xc;
            float a = av[idx], m2 = mx[idx];
            s = fmaf(ok ? a  : 0.f, saw[ky*7+kx], s);
            s = fmaf(ok ? m2 : 0.f, saw[49 + ky*7+kx], s);
        }
    }
    float sig = 1.0f/(1.0f+expf(-s));
#pragma unroll
    for (int c = 0; c < CC; ++c) {
        size_t idx = ((size_t)b*CC + c)*N1 + p;
        out[idx] = sig * ob[idx];
    }
}

} // anonymous namespace

extern "C" void kernel_launch(void* const* d_in, const int* in_sizes, int n_in,
                              void* d_out, int out_size, void* d_ws, size_t ws_size,
                              hipStream_t stream)
{
    const float* x    = (const float*)d_in[0];
    const float* ln1w = (const float*)d_in[1];
    const float* ln1b = (const float*)d_in[2];
    const float* temp = (const float*)d_in[3];
    const float* qkvw = (const float*)d_in[4];
    const float* qkvdw= (const float*)d_in[5];
    const float* projw= (const float*)d_in[6];
    const float* ln2w = (const float*)d_in[7];
    const float* ln2b = (const float*)d_in[8];
    const float* pinw = (const float*)d_in[9];
    const float* ffdw = (const float*)d_in[10];
    const float* poutw= (const float*)d_in[11];
    const float* caw1 = (const float*)d_in[12];
    const float* caw2 = (const float*)d_in[13];
    const float* saw  = (const float*)d_in[14];
    const float* sab  = (const float*)d_in[15];

    float* wsf  = (float*)d_ws;
    float* A4   = wsf;                               // 4 planes of (B,C,128,128)
    float* br1  = A4 + 4*PS2;
    float* br2  = br1 + NB1;
    float* x1b  = br2 + NB1;                         // tblock x1 / gfm out buffer
    float* tbA  = x1b + NB1;
    float* qkv  = tbA + PS2;                         // bf16 qkv conv out / bf16 pin_out
    float* qkvd = qkv + (size_t)BB*QKVC*N1;          // bf16 xhat; fp32 dwconv out; bf16 gate
    float* stats= qkvd + (size_t)BB*QKVC*N1;
    float* wqr  = stats + 4096;                      // repacked qkv w [48][144]
    float* wpr  = wqr + 48*QKVC;                     // repacked pin w [48][254]
    float* wor  = wpr + 48*PINC;                     // repacked pout w [127][48]
    float* chps = wor + HID*48;                      // chstat partial sums [192*8]
    float* chpm = chps + 192*CSEG;                   // chstat partial maxs
    float* savg = chpm + 192*CSEG;
    float* smax = savg + (size_t)BB*N1;

    k_repw<<<(48*QKVC+255)/256, 256, 0, stream>>>(qkvw, wqr, QKVC, 48);
    k_repw<<<(48*PINC+255)/256, 256, 0, stream>>>(pinw, wpr, PINC, 48);
    k_repw<<<(HID*48+255)/256, 256, 0, stream>>>(poutw, wor, 48, HID);

    auto tb = [&](const float* Xin, float* outp, int Hs, int Ws) {
        int Ns = Hs*Ws;
        int npix = BB*Ns;
        unsigned short* xhat = (unsigned short*)qkvd;   // dead before dw3v/dwgate write qkvd
        k_zero<<<3, 256, 0, stream>>>(stats, 768);
        k_ln<<<npix/512, 256, 0, stream>>>(Xin, ln1w, ln1b, xhat, Ns);
        dim3 gq(npix/512, QKVC/16);
        k_conv1x1<QKVC><<<gq, 256, 0, stream>>>(xhat, wqr, (unsigned short*)qkv, Ns);
        k_dw3v<<<(BB*QKVC*Ns/8)/256, 256, 0, stream>>>((const unsigned short*)qkv, qkvdw, qkvd, QKVC, Hs, Ws);
        k_qk_stats<<<BB*NHEAD*32, 256, 0, stream>>>(qkvd, stats, Ns);
        k_attn<<<1, 64, 0, stream>>>(stats, temp, stats + 768);
        dim3 g4(npix/256, 3);
        k_av_proj<<<g4, 256, 0, stream>>>(qkvd, stats + 768, projw, Xin, x1b, Ns);
        k_ln<<<npix/512, 256, 0, stream>>>(x1b, ln2w, ln2b, xhat, Ns);
        dim3 gp(npix/512, (PINC+15)/16);
        k_conv1x1<PINC><<<gp, 256, 0, stream>>>(xhat, wpr, (unsigned short*)qkv, Ns);
        k_dwgate<<<(BB*HID*Ns/8)/256, 256, 0, stream>>>((const unsigned short*)qkv, ffdw,
                                                        (unsigned short*)qkvd, Hs, Ws);
        dim3 g6(npix/512, 3);
        k_pout<<<g6, 256, 0, stream>>>((const unsigned short*)qkvd, wor, x1b, outp, Ns);
    };

    tb(x, br1, 256, 256);
    k_nlwt<<<(BB*CC*N2)/256, 256, 0, stream>>>(x, A4);
    tb(A4, tbA, 128, 128);
    k_inlwt<<<(BB*CC*N2)/256, 256, 0, stream>>>(tbA, A4, br2);
    dim3 gc(BB*96, CSEG);
    k_chstat_part<<<gc, 256, 0, stream>>>(br1, br2, chps, chpm);
    k_chstat_fin<<<1, 256, 0, stream>>>(chps, chpm, stats + 1344, stats + 1536);
    k_cw<<<1, 256, 0, stream>>>(stats + 1344, stats + 1536, caw1, caw2, stats + 1728);
    k_gfm_out<<<(BB*N1)/256, 256, 0, stream>>>(br1, br2, stats + 1728, x1b, savg, smax);
    k_final<<<(BB*N1)/256, 256, 0, stream>>>(savg, smax, saw, sab, x1b, (float*)d_out);
}

// Round 6
// 430.190 us; speedup vs baseline: 2.3355x; 1.1583x over previous
//
#include <hip/hip_runtime.h>
#include <math.h>

namespace {

constexpr int BB   = 2;
constexpr int CC   = 48;
constexpr int NHEAD= 8;
constexpr int CPH  = 6;     // channels per head
constexpr int HID  = 127;   // int(48*2.66)
constexpr int QKVC = 144;
constexpr int PINC = 254;
constexpr int N1   = 256*256;
constexpr int N2   = 128*128;
constexpr size_t PS2 = (size_t)BB*CC*N2;   // one nlwt plane
constexpr size_t NB1 = (size_t)BB*CC*N1;

using short8  = __attribute__((ext_vector_type(8))) short;
using floatx4 = __attribute__((ext_vector_type(4))) float;

__device__ __forceinline__ float b2f(unsigned short u) {
    unsigned int x = ((unsigned int)u) << 16;
    float f; __builtin_memcpy(&f, &x, 4); return f;
}
__device__ __forceinline__ unsigned short f2b(float f) {
    unsigned int x; __builtin_memcpy(&x, &f, 4);
    unsigned int r = (x + 0x7FFFu + ((x >> 16) & 1u)) >> 16;   // RNE
    return (unsigned short)r;
}
__device__ __forceinline__ unsigned int pack2(float lo, float hi) {
    return (unsigned int)f2b(lo) | ((unsigned int)f2b(hi) << 16);
}

// tanh-form GELU via hw exp (|err vs erf-GELU| < ~1e-3, within bf16 tolerance)
__device__ __forceinline__ float gelu_t(float x) {
    float z = 1.5957691216057308f * (x + 0.044715f * x * x * x);
    float e = __expf(z);
    return x * (1.0f - 1.0f / (e + 1.0f));
}

__global__ void k_zero(float* __restrict__ p, int n)
{
    int i = blockIdx.x*256 + threadIdx.x;
    if (i < n) p[i] = 0.f;
}

// generic repack w[oc][K] -> wt[c][oc] (fp32, used by pout)
__global__ void k_repw(const float* __restrict__ w, float* __restrict__ wt, int O, int K)
{
    int i = blockIdx.x*256 + threadIdx.x;
    if (i < O*K) {
        int c = i / O, oc = i - c*O;
        wt[c*O + oc] = w[oc*K + c];
    }
}

// pack conv weights [oc][48] fp32 -> per-lane MFMA A-fragments bf16
// frag index i = (t*2+s)*64 + lane ; lane holds A[row=oc=t*16+(l&15)][k=s*32+(l>>4)*8+j]
template<int OCR, int OCT>
__global__ void k_packw_mfma(const float* __restrict__ w, unsigned short* __restrict__ wf)
{
    int i = blockIdx.x*256 + threadIdx.x;
    if (i >= OCT*2*64) return;
    int lane = i & 63, ts = i >> 6;
    int s = ts & 1, t = ts >> 1;
    int oc = t*16 + (lane & 15);
    int kb = s*32 + (lane >> 4)*8;
    float v[8];
#pragma unroll
    for (int j = 0; j < 8; ++j) {
        int k = kb + j;
        v[j] = (oc < OCR && k < 48) ? w[oc*48 + k] : 0.f;
    }
    uint4 o;
    o.x = pack2(v[0], v[1]); o.y = pack2(v[2], v[3]);
    o.z = pack2(v[4], v[5]); o.w = pack2(v[6], v[7]);
    *(uint4*)(wf + (size_t)i*8) = o;
}

// ---------------- LN (channel): fp32 in -> bf16 LN'd out, PIXEL-MAJOR [px][48] ----------------
__global__ __launch_bounds__(256) void k_ln_t(const float* __restrict__ X,
                       const float* __restrict__ lw, const float* __restrict__ lb,
                       unsigned short* __restrict__ xh, int Ns)
{
    int g = blockIdx.x*256 + threadIdx.x;      // over BB*Ns/2
    int half = Ns >> 1;
    int b = g / half, pp = (g - b*half)*2;
    const float* xb = X + (size_t)b*CC*Ns + pp;
    float v0[CC], v1[CC];
    float s0=0.f, s20=0.f, s1=0.f, s21=0.f;
#pragma unroll
    for (int c = 0; c < CC; ++c) {
        float2 v = *(const float2*)(xb + (size_t)c*Ns);
        v0[c]=v.x; v1[c]=v.y;
        s0 += v.x; s20 = fmaf(v.x,v.x,s20);
        s1 += v.y; s21 = fmaf(v.y,v.y,s21);
    }
    float mu0 = s0*(1.0f/CC), mu1 = s1*(1.0f/CC);
    float i0 = 1.0f/sqrtf(s20*(1.0f/CC)-mu0*mu0+1e-5f);
    float i1 = 1.0f/sqrtf(s21*(1.0f/CC)-mu1*mu1+1e-5f);
    unsigned short* r0 = xh + ((size_t)b*Ns + pp)*48;
    unsigned short* r1 = r0 + 48;
#pragma unroll
    for (int j = 0; j < 6; ++j) {
        uint4 o0, o1;
        float y[8], z[8];
#pragma unroll
        for (int e = 0; e < 8; ++e) {
            int c = j*8 + e;
            float w = lw[c], bb2 = lb[c];
            y[e] = (v0[c]-mu0)*i0*w + bb2;
            z[e] = (v1[c]-mu1)*i1*w + bb2;
        }
        o0.x = pack2(y[0],y[1]); o0.y = pack2(y[2],y[3]);
        o0.z = pack2(y[4],y[5]); o0.w = pack2(y[6],y[7]);
        o1.x = pack2(z[0],z[1]); o1.y = pack2(z[2],z[3]);
        o1.z = pack2(z[4],z[5]); o1.w = pack2(z[6],z[7]);
        *(uint4*)(r0 + j*8) = o0;
        *(uint4*)(r1 + j*8) = o1;
    }
}

// ---------------- 1x1 conv via MFMA: xh [px][48] bf16 -> out [oc][px] bf16 ----------------
// one wave = 16-px tile; K=48 as 2 steps of 32 (upper 16 of step 1 zero-padded in weights)
template<int OCR, int OCT>
__global__ __launch_bounds__(256) void k_conv_mfma(const unsigned short* __restrict__ xh,
                       const unsigned short* __restrict__ wf,
                       unsigned short* __restrict__ out, int Ns)
{
    int wid = (blockIdx.x*256 + (int)threadIdx.x) >> 6;
    int lane = threadIdx.x & 63;
    int tpb = Ns >> 4;                 // 16-px tiles per image
    int b = wid / tpb, pxt = wid - b*tpb;
    int px0 = pxt << 4;
    int col = lane & 15, grp = lane >> 4;
    const unsigned short* xb = xh + ((size_t)b*Ns + px0 + col)*48 + grp*8;
    short8 b0 = *(const short8*)(xb);        // k = grp*8 + j
    short8 b1 = *(const short8*)(xb + 32);   // k = 32 + grp*8 + j (k>=48 garbage * zero weight)
    unsigned short* ob = out + (size_t)b*OCR*Ns + px0 + col;
    int ocb0 = grp*4;
#pragma unroll
    for (int t = 0; t < OCT; ++t) {
        floatx4 acc = {};
        short8 a0 = *(const short8*)(wf + (size_t)((t*2+0)*64 + lane)*8);
        short8 a1 = *(const short8*)(wf + (size_t)((t*2+1)*64 + lane)*8);
        acc = __builtin_amdgcn_mfma_f32_16x16x32_bf16(a0, b0, acc, 0, 0, 0);
        acc = __builtin_amdgcn_mfma_f32_16x16x32_bf16(a1, b1, acc, 0, 0, 0);
#pragma unroll
        for (int r = 0; r < 4; ++r) {
            int oc = t*16 + ocb0 + r;
            if (OCR % 16 == 0 || oc < OCR)
                ob[(size_t)oc*Ns] = f2b(acc[r]);
        }
    }
}

// ---------------- row-vectorized depthwise 3x3 (zero pad), 8 px/thread ----------------
__device__ __forceinline__ void load_row10(const unsigned short* __restrict__ p,
                                           bool rok, bool lok, bool rrok, float (&f)[10])
{
    if (rok) {
        uint4 cv = *(const uint4*)p;            // 8 bf16, 16B aligned
        unsigned int u0=cv.x,u1=cv.y,u2=cv.z,u3=cv.w;
        f[1]=b2f((unsigned short)(u0&0xffffu)); f[2]=b2f((unsigned short)(u0>>16));
        f[3]=b2f((unsigned short)(u1&0xffffu)); f[4]=b2f((unsigned short)(u1>>16));
        f[5]=b2f((unsigned short)(u2&0xffffu)); f[6]=b2f((unsigned short)(u2>>16));
        f[7]=b2f((unsigned short)(u3&0xffffu)); f[8]=b2f((unsigned short)(u3>>16));
        f[0] = lok  ? b2f(p[-1]) : 0.f;
        f[9] = rrok ? b2f(p[8])  : 0.f;
    } else {
#pragma unroll
        for (int i = 0; i < 10; ++i) f[i] = 0.f;
    }
}

__device__ __forceinline__ void dw8(const unsigned short* __restrict__ plane,
                                    const float* __restrict__ w9,
                                    int y, int x0, int Hs, int Ws, float (&o)[8])
{
#pragma unroll
    for (int i = 0; i < 8; ++i) o[i] = 0.f;
#pragma unroll
    for (int dy = 0; dy < 3; ++dy) {
        int r = y + dy - 1;
        bool rok = (r >= 0) && (r < Hs);
        float f[10];
        const unsigned short* p = plane + (size_t)(rok ? r : 0)*Ws + x0;
        load_row10(p, rok, x0 > 0, x0 + 8 < Ws, f);
        float w0 = w9[dy*3], w1 = w9[dy*3+1], w2 = w9[dy*3+2];
#pragma unroll
        for (int i = 0; i < 8; ++i)
            o[i] = fmaf(f[i], w0, fmaf(f[i+1], w1, fmaf(f[i+2], w2, o[i])));
    }
}

// qkv path: bf16 in -> fp32 out
__global__ __launch_bounds__(256) void k_dw3v(const unsigned short* __restrict__ in,
                      const float* __restrict__ w,
                      float* __restrict__ out, int nch, int Hs, int Ws)
{
    int Ns = Hs * Ws, ng = Ns >> 3, wq = Ws >> 3;
    int g = blockIdx.x*256 + threadIdx.x;    // over BB*nch*ng
    int t = g % ng, bc = g / ng;
    int c = bc % nch;
    int y = t / wq, x0 = (t - y*wq) << 3;
    float o[8];
    dw8(in + (size_t)bc*Ns, w + c*9, y, x0, Hs, Ws, o);
    float4* ob = (float4*)(out + (size_t)bc*Ns + y*Ws + x0);
    ob[0] = make_float4(o[0],o[1],o[2],o[3]);
    ob[1] = make_float4(o[4],o[5],o[6],o[7]);
}

// ffn path: two planes + gelu gate -> bf16
__global__ __launch_bounds__(256) void k_dwgate(const unsigned short* __restrict__ pin,
                         const float* __restrict__ dww,
                         unsigned short* __restrict__ gate, int Hs, int Ws)
{
    int Ns = Hs * Ws, ng = Ns >> 3, wq = Ws >> 3;
    int g = blockIdx.x*256 + threadIdx.x;    // over BB*HID*ng
    int t = g % ng, bc = g / ng;
    int b = bc / HID, c = bc - b*HID;
    int y = t / wq, x0 = (t - y*wq) << 3;
    float d1[8], d2[8];
    dw8(pin + ((size_t)b*PINC + c)*Ns,       dww + c*9,         y, x0, Hs, Ws, d1);
    dw8(pin + ((size_t)b*PINC + HID + c)*Ns, dww + (c+HID)*9,   y, x0, Hs, Ws, d2);
    uint4 r;
    r.x = pack2(gelu_t(d1[0])*d2[0], gelu_t(d1[1])*d2[1]);
    r.y = pack2(gelu_t(d1[2])*d2[2], gelu_t(d1[3])*d2[3]);
    r.z = pack2(gelu_t(d1[4])*d2[4], gelu_t(d1[5])*d2[5]);
    r.w = pack2(gelu_t(d1[6])*d2[6], gelu_t(d1[7])*d2[7]);
    *(uint4*)(gate + (size_t)bc*Ns + y*Ws + x0) = r;
}

// ---------------- q/k norms + gram reduction ----------------
__global__ __launch_bounds__(256) void k_qk_stats(const float* __restrict__ qkvd,
                                                  float* __restrict__ st, int Ns)
{
    const int NBLK = 32;
    int bh = blockIdx.x / NBLK, blk = blockIdx.x % NBLK;
    int b = bh / NHEAD, h = bh % NHEAD;
    const float* qb = qkvd + ((size_t)b*QKVC + h*CPH)*Ns;
    const float* kb = qkvd + ((size_t)b*QKVC + 48 + h*CPH)*Ns;
    float vals[48];
#pragma unroll
    for (int i = 0; i < 48; ++i) vals[i] = 0.f;
    for (int n = blk*256 + (int)threadIdx.x; n < Ns; n += NBLK*256) {
        float qv[CPH], kv[CPH];
#pragma unroll
        for (int i = 0; i < CPH; ++i) { qv[i] = qb[(size_t)i*Ns + n]; kv[i] = kb[(size_t)i*Ns + n]; }
#pragma unroll
        for (int i = 0; i < CPH; ++i) {
            vals[i]   = fmaf(qv[i], qv[i], vals[i]);
            vals[6+i] = fmaf(kv[i], kv[i], vals[6+i]);
        }
#pragma unroll
        for (int i = 0; i < CPH; ++i)
#pragma unroll
            for (int j = 0; j < CPH; ++j)
                vals[12 + i*6 + j] = fmaf(qv[i], kv[j], vals[12 + i*6 + j]);
    }
    __shared__ float red[4][48];
    int lane = threadIdx.x & 63, wave = threadIdx.x >> 6;
#pragma unroll
    for (int i = 0; i < 48; ++i) {
        float v = vals[i];
#pragma unroll
        for (int off = 32; off > 0; off >>= 1) v += __shfl_down(v, off);
        if (lane == 0) red[wave][i] = v;
    }
    __syncthreads();
    if ((int)threadIdx.x < 48) {
        int i = threadIdx.x;
        float v = red[0][i] + red[1][i] + red[2][i] + red[3][i];
        float* dst;
        if (i < 6)       dst = st + b*48 + h*CPH + i;
        else if (i < 12) dst = st + 96 + b*48 + h*CPH + (i-6);
        else             dst = st + 192 + (b*NHEAD+h)*36 + (i-12);
        atomicAdd(dst, v);
    }
}

// ---------------- tiny softmax over 6x6 per (b,h) ----------------
__global__ void k_attn(const float* __restrict__ st, const float* __restrict__ temp,
                       float* __restrict__ ao)
{
    int t = threadIdx.x;
    if (t >= BB*NHEAD) return;
    int b = t / NHEAD, h = t % NHEAD;
    const float* sqq = st + b*48 + h*CPH;
    const float* sqk = st + 96 + b*48 + h*CPH;
    const float* g   = st + 192 + (b*NHEAD+h)*36;
    float T = temp[h];
    float nq[CPH], nk[CPH];
#pragma unroll
    for (int i = 0; i < CPH; ++i) {
        nq[i] = fmaxf(sqrtf(sqq[i]), 1e-12f);
        nk[i] = fmaxf(sqrtf(sqk[i]), 1e-12f);
    }
    float* out = ao + (b*NHEAD+h)*36;
#pragma unroll
    for (int c = 0; c < CPH; ++c) {
        float l[CPH]; float m = -1e30f;
#pragma unroll
        for (int d = 0; d < CPH; ++d) {
            l[d] = g[c*6+d] / (nq[c]*nk[d]) * T;
            m = fmaxf(m, l[d]);
        }
        float ssum = 0.f;
#pragma unroll
        for (int d = 0; d < CPH; ++d) { l[d] = expf(l[d]-m); ssum += l[d]; }
        float r = 1.0f/ssum;
#pragma unroll
        for (int d = 0; d < CPH; ++d) out[c*6+d] = l[d]*r;
    }
}

// ---------------- attn @ v + proj 1x1 + residual (16-oc chunks) ----------------
__global__ __launch_bounds__(256) void k_av_proj(const float* __restrict__ qkvd, const float* __restrict__ attn,
                          const float* __restrict__ projw, const float* __restrict__ X,
                          float* __restrict__ x1, int Ns)
{
    int g = blockIdx.x*256 + threadIdx.x;
    int b = g / Ns, p = g - b*Ns;
    int ocb = blockIdx.y * 16;
    const float* vb = qkvd + ((size_t)b*QKVC + 96)*Ns + p;
    float vv[CC];
#pragma unroll
    for (int c = 0; c < CC; ++c) vv[c] = vb[(size_t)c*Ns];
    const float* at = attn + b*288;
    float o[CC];
#pragma unroll
    for (int h = 0; h < NHEAD; ++h)
#pragma unroll
        for (int cc = 0; cc < CPH; ++cc) {
            float acc = 0.f;
#pragma unroll
            for (int d = 0; d < CPH; ++d)
                acc = fmaf(at[(h*CPH+cc)*CPH + d], vv[h*CPH + d], acc);
            o[h*CPH+cc] = acc;
        }
    const float* xb = X + (size_t)b*CC*Ns + p;
    float* ob = x1 + (size_t)b*CC*Ns + p;
    float acc[16];
#pragma unroll
    for (int i = 0; i < 16; ++i) acc[i] = 0.f;
#pragma unroll
    for (int c = 0; c < CC; ++c) {
#pragma unroll
        for (int i = 0; i < 16; ++i)
            acc[i] = fmaf(o[c], projw[(ocb+i)*CC + c], acc[i]);
    }
#pragma unroll
    for (int i = 0; i < 16; ++i)
        ob[(size_t)(ocb+i)*Ns] = xb[(size_t)(ocb+i)*Ns] + acc[i];
}

// ---------------- ffn part 2: 1x1 conv 127->48 + residual ----------------
template<int U>
__device__ __forceinline__ void pout_chunk(const unsigned short* __restrict__ gb, int c0, int Ns,
                                           const float* __restrict__ wt, int ocb,
                                           float (&a0)[16], float (&a1)[16])
{
    unsigned int gv[U];
#pragma unroll
    for (int u = 0; u < U; ++u)
        gv[u] = *(const unsigned int*)(gb + (size_t)(c0+u)*Ns);
#pragma unroll
    for (int u = 0; u < U; ++u) {
        float t0 = b2f((unsigned short)(gv[u] & 0xffffu));
        float t1 = b2f((unsigned short)(gv[u] >> 16));
        const float* wr = wt + (c0+u)*48 + ocb;
#pragma unroll
        for (int i = 0; i < 16; ++i) {
            float w = wr[i];
            a0[i] = fmaf(t0, w, a0[i]);
            a1[i] = fmaf(t1, w, a1[i]);
        }
    }
}

__global__ __launch_bounds__(256) void k_pout(const unsigned short* __restrict__ gate,
                       const float* __restrict__ wt, const float* __restrict__ x1,
                       float* __restrict__ out, int Ns)
{
    int g = blockIdx.x*256 + threadIdx.x;      // over BB*Ns/2
    int half = Ns >> 1;
    int b = g / half, pp = (g - b*half)*2;
    int ocb = blockIdx.y * 16;
    const unsigned short* gb = gate + (size_t)b*HID*Ns + pp;
    float a0[16], a1[16];
#pragma unroll
    for (int i = 0; i < 16; ++i) { a0[i] = 0.f; a1[i] = 0.f; }
    int c = 0;
    for (; c + 8 <= HID; c += 8)
        pout_chunk<8>(gb, c, Ns, wt, ocb, a0, a1);
    pout_chunk<7>(gb, c, Ns, wt, ocb, a0, a1);   // 120..126
    const float* xb = x1 + (size_t)b*CC*Ns + pp;
    float* ob = out + (size_t)b*CC*Ns + pp;
#pragma unroll
    for (int i = 0; i < 16; ++i) {
        float2 xv = *(const float2*)(xb + (size_t)(ocb+i)*Ns);
        float2 o; o.x = xv.x + a0[i]; o.y = xv.y + a1[i];
        *(float2*)(ob + (size_t)(ocb+i)*Ns) = o;
    }
}

// ---------------- nlwt ----------------
__global__ __launch_bounds__(256) void k_nlwt(const float* __restrict__ X, float* __restrict__ A4)
{
    int g = blockIdx.x*256 + threadIdx.x;   // over BB*CC*N2
    int n = g & (N2-1); int bc = g >> 14;
    int h1 = n >> 7, w1 = n & 127;
    int hb = (h1+1)&127, wb = (w1+1)&127;
    const float* xp = X + (size_t)bc * N1;
    float t1, t2, t3, t4;
    {
        int y=h1, z=w1;
        float c0=xp[(2*y)*256+2*z], c1=xp[(2*y)*256+2*z+1], c2=xp[(2*y+1)*256+2*z], c3=xp[(2*y+1)*256+2*z+1];
        t1 = 0.5f*(-c0 - c1 - c2 + c3);
    }
    {
        int y=hb, z=w1;
        float c0=xp[(2*y)*256+2*z], c1=xp[(2*y)*256+2*z+1], c2=xp[(2*y+1)*256+2*z], c3=xp[(2*y+1)*256+2*z+1];
        t2 = 0.5f*( c0 - c1 + c2 + c3);
    }
    {
        int y=h1, z=wb;
        float c0=xp[(2*y)*256+2*z], c1=xp[(2*y)*256+2*z+1], c2=xp[(2*y+1)*256+2*z], c3=xp[(2*y+1)*256+2*z+1];
        t3 = 0.5f*( c0 + c1 - c2 + c3);
    }
    {
        int y=hb, z=wb;
        float c0=xp[(2*y)*256+2*z], c1=xp[(2*y)*256+2*z+1], c2=xp[(2*y+1)*256+2*z], c3=xp[(2*y+1)*256+2*z+1];
        t4 = 0.5f*( c0 - c1 - c2 - c3);
    }
    size_t o = (size_t)bc*N2 + n;
    A4[o]           = -t1 + t2 + t3 - t4;
    A4[PS2 + o]     = -t1 - t2 - t3 - t4;
    A4[2*PS2 + o]   = -t1 - t2 + t3 + t4;
    A4[3*PS2 + o]   =  t1 - t2 + t3 - t4;
}

// ---------------- inlwt ----------------
__global__ __launch_bounds__(256) void k_inlwt(const float* __restrict__ Ain, const float* __restrict__ A4,
                        float* __restrict__ out)
{
    int g = blockIdx.x*256 + threadIdx.x;   // over BB*CC*N2
    int n = g & (N2-1); int bc = g >> 14;
    int h1 = n >> 7, w1 = n & 127;
    int hm = (h1-1)&127, wm = (w1-1)&127;
    const float* I0 = Ain + (size_t)bc*N2;
    const float* I1 = A4 + PS2   + (size_t)bc*N2;
    const float* I2 = A4 + 2*PS2 + (size_t)bc*N2;
    const float* I3 = A4 + 3*PS2 + (size_t)bc*N2;
    int i00 = h1*128+w1, i10 = hm*128+w1, i01 = h1*128+wm, i11 = hm*128+wm;
    float t1, t2, t3, t4;
    { float a=I0[i00], b2=I1[i00], c2=I2[i00], d2=I3[i00]; t1 = -a - b2 - c2 + d2; }
    { float a=I0[i10], b2=I1[i10], c2=I2[i10], d2=I3[i10]; t2 =  a - b2 - c2 - d2; }
    { float a=I0[i01], b2=I1[i01], c2=I2[i01], d2=I3[i01]; t3 =  a - b2 + c2 + d2; }
    { float a=I0[i11], b2=I1[i11], c2=I2[i11], d2=I3[i11]; t4 = -a - b2 + c2 - d2; }
    float y00 = 0.125f*(-t1 + t2 + t3 + t4);
    float y01 = 0.125f*(-t1 - t2 + t3 - t4);
    float y10 = 0.125f*(-t1 + t2 - t3 - t4);
    float y11 = 0.125f*( t1 + t2 + t3 - t4);
    float* ob = out + (size_t)bc * N1;
    int oy = h1*2, ox = w1*2;
    ob[(size_t)oy*256 + ox]       = y00;
    ob[(size_t)oy*256 + ox + 1]   = y01;
    ob[(size_t)(oy+1)*256 + ox]   = y10;
    ob[(size_t)(oy+1)*256 + ox+1] = y11;
}

// ---------------- gfm: channel stats, two-stage ----------------
constexpr int CSEG = 8;
__global__ __launch_bounds__(256) void k_chstat_part(const float* __restrict__ b1, const float* __restrict__ b2,
                         float* __restrict__ ps, float* __restrict__ pm)
{
    int bc = blockIdx.x;            // 0..BB*96-1
    int seg = blockIdx.y;           // 0..CSEG-1
    int b = bc / 96, ch = bc % 96;
    const float* src = (ch < 48 ? b1 + ((size_t)b*CC + ch)*N1
                                : b2 + ((size_t)b*CC + (ch-48))*N1) + (size_t)seg*(N1/CSEG);
    const float4* s4 = (const float4*)src;
    float s = 0.f, m = -1e30f;
    for (int i = threadIdx.x; i < N1/CSEG/4; i += 256) {
        float4 v = s4[i];
        s += v.x+v.y+v.z+v.w;
        m = fmaxf(m, fmaxf(fmaxf(v.x,v.y), fmaxf(v.z,v.w)));
    }
    int lane = threadIdx.x & 63, wave = threadIdx.x >> 6;
    __shared__ float rs[4], rm[4];
#pragma unroll
    for (int off = 32; off > 0; off >>= 1) {
        s += __shfl_down(s, off);
        m = fmaxf(m, __shfl_down(m, off));
    }
    if (lane == 0) { rs[wave] = s; rm[wave] = m; }
    __syncthreads();
    if (threadIdx.x == 0) {
        ps[bc*CSEG + seg] = rs[0]+rs[1]+rs[2]+rs[3];
        pm[bc*CSEG + seg] = fmaxf(fmaxf(rm[0],rm[1]), fmaxf(rm[2],rm[3]));
    }
}

__global__ void k_chstat_fin(const float* __restrict__ ps, const float* __restrict__ pm,
                             float* __restrict__ avg, float* __restrict__ mxo)
{
    int t = threadIdx.x;
    if (t >= BB*96) return;
    float s = 0.f, m = -1e30f;
#pragma unroll
    for (int j = 0; j < CSEG; ++j) {
        s += ps[t*CSEG+j];
        m = fmaxf(m, pm[t*CSEG+j]);
    }
    avg[t] = s*(1.0f/N1);
    mxo[t] = m;
}

// ---------------- gfm: channel attention MLP ----------------
__global__ void k_cw(const float* __restrict__ avg, const float* __restrict__ mx,
                     const float* __restrict__ w1, const float* __restrict__ w2,
                     float* __restrict__ cw)
{
    int t = threadIdx.x;
    if (t >= BB*96) return;
    int b = t / 96, o = t % 96;
    float ta[6], tm[6];
#pragma unroll
    for (int j = 0; j < 6; ++j) {
        float sa = 0.f, sm = 0.f;
        for (int i = 0; i < 96; ++i) {
            float w = w1[j*96+i];
            sa = fmaf(w, avg[b*96+i], sa);
            sm = fmaf(w, mx[b*96+i], sm);
        }
        ta[j] = sa > 0.f ? sa : 0.f;
        tm[j] = sm > 0.f ? sm : 0.f;
    }
    float ua = 0.f, um = 0.f;
#pragma unroll
    for (int j = 0; j < 6; ++j) {
        ua = fmaf(w2[o*6+j], ta[j], ua);
        um = fmaf(w2[o*6+j], tm[j], um);
    }
    float z = ua + um;
    cw[t] = 1.0f/(1.0f+expf(-z));
}

// ---------------- gfm: weighted combine + spatial stats ----------------
__global__ __launch_bounds__(256) void k_gfm_out(const float* __restrict__ b1, const float* __restrict__ b2,
                          const float* __restrict__ cw, float* __restrict__ ob,
                          float* __restrict__ savg, float* __restrict__ smax)
{
    int g = blockIdx.x*256 + threadIdx.x;   // BB*N1
    int b = g >> 16, p = g & (N1-1);
    float s = 0.f, m = -1e30f;
#pragma unroll
    for (int c = 0; c < CC; ++c) {
        size_t idx = ((size_t)b*CC + c)*N1 + p;
        float o = cw[b*96 + c]*b1[idx] + cw[b*96 + 48 + c]*b2[idx];
        ob[idx] = o;
        s += o; m = fmaxf(m, o);
    }
    savg[(size_t)b*N1 + p] = s*(1.0f/CC);
    smax[(size_t)b*N1 + p] = m;
}

// ---------------- gfm: 7x7 spatial attention + final multiply ----------------
__global__ __launch_bounds__(256) void k_final(const float* __restrict__ savg, const float* __restrict__ smax,
                        const float* __restrict__ saw, const float* __restrict__ sab,
                        const float* __restrict__ ob, float* __restrict__ out)
{
    int g = blockIdx.x*256 + threadIdx.x;
    int b = g >> 16, p = g & (N1-1);
    int y = p >> 8, x = p & 255;
    float s = sab[0];
    const float* av = savg + (size_t)b*N1;
    const float* mx = smax + (size_t)b*N1;
#pragma unroll
    for (int ky = 0; ky < 7; ++ky) {
        int yy = y + ky - 3;
        bool yok = (yy >= 0) && (yy < 256);
        int yc = yy < 0 ? 0 : (yy > 255 ? 255 : yy);
#pragma unroll
        for (int kx = 0; kx < 7; ++kx) {
            int xx = x + kx - 3;
            bool ok = yok && (xx >= 0) && (xx < 256);
            int xc = xx < 0 ? 0 : (xx > 255 ? 255 : xx);
            int idx = yc*256 + xc;
            float a = av[idx], m2 = mx[idx];
            s = fmaf(ok ? a  : 0.f, saw[ky*7+kx], s);
            s = fmaf(ok ? m2 : 0.f, saw[49 + ky*7+kx], s);
        }
    }
    float sig = 1.0f/(1.0f+expf(-s));
#pragma unroll
    for (int c = 0; c < CC; ++c) {
        size_t idx = ((size_t)b*CC + c)*N1 + p;
        out[idx] = sig * ob[idx];
    }
}

} // anonymous namespace

extern "C" void kernel_launch(void* const* d_in, const int* in_sizes, int n_in,
                              void* d_out, int out_size, void* d_ws, size_t ws_size,
                              hipStream_t stream)
{
    const float* x    = (const float*)d_in[0];
    const float* ln1w = (const float*)d_in[1];
    const float* ln1b = (const float*)d_in[2];
    const float* temp = (const float*)d_in[3];
    const float* qkvw = (const float*)d_in[4];
    const float* qkvdw= (const float*)d_in[5];
    const float* projw= (const float*)d_in[6];
    const float* ln2w = (const float*)d_in[7];
    const float* ln2b = (const float*)d_in[8];
    const float* pinw = (const float*)d_in[9];
    const float* ffdw = (const float*)d_in[10];
    const float* poutw= (const float*)d_in[11];
    const float* caw1 = (const float*)d_in[12];
    const float* caw2 = (const float*)d_in[13];
    const float* saw  = (const float*)d_in[14];
    const float* sab  = (const float*)d_in[15];

    float* wsf  = (float*)d_ws;
    float* A4   = wsf;                               // 4 planes of (B,C,128,128)
    float* br1  = A4 + 4*PS2;
    float* br2  = br1 + NB1;
    float* x1b  = br2 + NB1;                         // tblock x1 / gfm out buffer
    float* tbA  = x1b + NB1;
    float* qkv  = tbA + PS2;                         // bf16 qkv conv out / bf16 pin_out
    float* qkvd = qkv + (size_t)BB*QKVC*N1;          // bf16 xhat(pixel-major); fp32 dwconv out; bf16 gate
    float* stats= qkvd + (size_t)BB*QKVC*N1;
    float* wfqf = stats + 4096;                      // mfma-packed qkv w: 9*2*64*8 ushorts
    float* wfpf = wfqf + 4608;                       // mfma-packed pin w: 16*2*64*8 ushorts
    float* wor  = wfpf + 8192;                       // repacked pout w [127][48] fp32
    float* chps = wor + HID*48;                      // chstat partial sums [192*8]
    float* chpm = chps + 192*CSEG;                   // chstat partial maxs
    float* savg = chpm + 192*CSEG;
    float* smax = savg + (size_t)BB*N1;

    unsigned short* wfq = (unsigned short*)wfqf;
    unsigned short* wfp = (unsigned short*)wfpf;

    k_packw_mfma<QKVC, 9><<<(9*2*64+255)/256, 256, 0, stream>>>(qkvw, wfq);
    k_packw_mfma<PINC, 16><<<(16*2*64+255)/256, 256, 0, stream>>>(pinw, wfp);
    k_repw<<<(HID*48+255)/256, 256, 0, stream>>>(poutw, wor, 48, HID);

    auto tb = [&](const float* Xin, float* outp, int Hs, int Ws) {
        int Ns = Hs*Ws;
        int npix = BB*Ns;
        unsigned short* xhat = (unsigned short*)qkvd;   // dead before dw3v/dwgate write qkvd
        k_zero<<<3, 256, 0, stream>>>(stats, 768);
        k_ln_t<<<npix/512, 256, 0, stream>>>(Xin, ln1w, ln1b, xhat, Ns);
        k_conv_mfma<QKVC, 9><<<npix/64, 256, 0, stream>>>(xhat, wfq, (unsigned short*)qkv, Ns);
        k_dw3v<<<(BB*QKVC*Ns/8)/256, 256, 0, stream>>>((const unsigned short*)qkv, qkvdw, qkvd, QKVC, Hs, Ws);
        k_qk_stats<<<BB*NHEAD*32, 256, 0, stream>>>(qkvd, stats, Ns);
        k_attn<<<1, 64, 0, stream>>>(stats, temp, stats + 768);
        dim3 g4(npix/256, 3);
        k_av_proj<<<g4, 256, 0, stream>>>(qkvd, stats + 768, projw, Xin, x1b, Ns);
        k_ln_t<<<npix/512, 256, 0, stream>>>(x1b, ln2w, ln2b, xhat, Ns);
        k_conv_mfma<PINC, 16><<<npix/64, 256, 0, stream>>>(xhat, wfp, (unsigned short*)qkv, Ns);
        k_dwgate<<<(BB*HID*Ns/8)/256, 256, 0, stream>>>((const unsigned short*)qkv, ffdw,
                                                        (unsigned short*)qkvd, Hs, Ws);
        dim3 g6(npix/512, 3);
        k_pout<<<g6, 256, 0, stream>>>((const unsigned short*)qkvd, wor, x1b, outp, Ns);
    };

    tb(x, br1, 256, 256);
    k_nlwt<<<(BB*CC*N2)/256, 256, 0, stream>>>(x, A4);
    tb(A4, tbA, 128, 128);
    k_inlwt<<<(BB*CC*N2)/256, 256, 0, stream>>>(tbA, A4, br2);
    dim3 gc(BB*96, CSEG);
    k_chstat_part<<<gc, 256, 0, stream>>>(br1, br2, chps, chpm);
    k_chstat_fin<<<1, 256, 0, stream>>>(chps, chpm, stats + 1344, stats + 1536);
    k_cw<<<1, 256, 0, stream>>>(stats + 1344, stats + 1536, caw1, caw2, stats + 1728);
    k_gfm_out<<<(BB*N1)/256, 256, 0, stream>>>(br1, br2, stats + 1728, x1b, savg, smax);
    k_final<<<(BB*N1)/256, 256, 0, stream>>>(savg, smax, saw, sab, x1b, (float*)d_out);
}